// Round 14
// baseline (701.524 us; speedup 1.0000x reference)
//
#include <hip/hip_runtime.h>
#include <hip/hip_bf16.h>

#define NTOK 16384
#define CDIM 768
#define FDIM 3072
#define NEXP 8
#define NSLOT 32768   // NTOK * TOPK
#define HBLK 128      // histogram blocks (NSLOT / 256)
#define MAXT256 135   // NSLOT/256 + NEXP - 1

typedef __attribute__((ext_vector_type(8))) short bf16x8;
typedef __attribute__((ext_vector_type(4))) float f32x4;
typedef __attribute__((ext_vector_type(8))) unsigned short u16x8;

__device__ __forceinline__ unsigned short f2bf(float f) {
  unsigned int u = __float_as_uint(f);
  u += 0x7FFFu + ((u >> 16) & 1u);   // RNE
  return (unsigned short)(u >> 16);
}
__device__ __forceinline__ float bf2f(unsigned short h) {
  return __uint_as_float((unsigned int)h << 16);
}

// GELU via Page-1977 logistic approx of Phi; |err| <= ~3e-4 << bf16 ulp of H
__device__ __forceinline__ float fast_gelu(float x) {
  float x2 = x * x;
  float z = x * __builtin_fmaf(0.070565402f, x2, 1.5975981f);
  float s = __builtin_amdgcn_rcpf(1.0f + __expf(-z));
  return x * s;
}

__device__ __forceinline__ void async16(const void* g, void* l) {
  __builtin_amdgcn_global_load_lds(
      (const __attribute__((address_space(1))) unsigned int*)g,
      (__attribute__((address_space(3))) unsigned int*)l, 16, 0, 0);
}

#define BARRIER() asm volatile("s_barrier" ::: "memory")
#define LGK0()    asm volatile("s_waitcnt lgkmcnt(0)" ::: "memory")
#define VMC(n)    asm volatile("s_waitcnt vmcnt(" #n ")" ::: "memory")

// ---------------- transpose + fp32->bf16 convert ----------------
__global__ __launch_bounds__(256)
void k_transpose(const float* __restrict__ src, unsigned short* __restrict__ dst,
                 int R, int Cc)
{
  __shared__ float tle[32][33];
  int e = blockIdx.z;
  int c0 = blockIdx.x * 32, r0 = blockIdx.y * 32;
  int tx = threadIdx.x & 31, ty = threadIdx.x >> 5;
  const float* s = src + (size_t)e * R * Cc;
  unsigned short* d = dst + (size_t)e * R * Cc;
#pragma unroll
  for (int i = 0; i < 4; ++i)
    tle[ty + i * 8][tx] = s[(size_t)(r0 + ty + i * 8) * Cc + c0 + tx];
  __syncthreads();
#pragma unroll
  for (int i = 0; i < 4; ++i)
    d[(size_t)(c0 + ty + i * 8) * R + r0 + tx] = f2bf(tle[tx][ty + i * 8]);
}

// ---------------- router ----------------
__global__ __launch_bounds__(256)
void k_router(const float* __restrict__ x, const float* __restrict__ rw,
              int* __restrict__ tk_e, float* __restrict__ tk_w)
{
  __shared__ float srw[NEXP * CDIM];
  int tid = threadIdx.x;
#pragma unroll
  for (int i = 0; i < (NEXP * CDIM / 4) / 256; ++i)
    ((float4*)srw)[tid + i * 256] = ((const float4*)rw)[tid + i * 256];
  __syncthreads();
  int lane = tid & 63, wid = tid >> 6;
  int t = blockIdx.x * 4 + wid;
  float a[NEXP];
#pragma unroll
  for (int e = 0; e < NEXP; ++e) a[e] = 0.f;
  const float* xr = x + (size_t)t * CDIM;
#pragma unroll
  for (int c = 0; c < CDIM / 64; ++c) {
    float xv = xr[c * 64 + lane];
#pragma unroll
    for (int e = 0; e < NEXP; ++e) a[e] += xv * srw[e * CDIM + c * 64 + lane];
  }
#pragma unroll
  for (int e = 0; e < NEXP; ++e) {
#pragma unroll
    for (int off = 32; off; off >>= 1) a[e] += __shfl_xor(a[e], off);
  }
  if (lane == 0) {
    int i0 = 0; float l0 = a[0];
#pragma unroll
    for (int e = 1; e < NEXP; ++e) if (a[e] > l0) { l0 = a[e]; i0 = e; }
    int i1 = -1; float l1 = -1e30f;
#pragma unroll
    for (int e = 0; e < NEXP; ++e) if (e != i0 && a[e] > l1) { l1 = a[e]; i1 = e; }
    float w0 = 1.f / (1.f + expf(l1 - l0));
    tk_e[2 * t] = i0;     tk_e[2 * t + 1] = i1;
    tk_w[2 * t] = w0;     tk_w[2 * t + 1] = 1.f - w0;
  }
}

// ---------------- per-block expert histogram ----------------
__global__ __launch_bounds__(256)
void k_hist(const int* __restrict__ tk_e, int* __restrict__ blockhist)
{
  __shared__ int h[NEXP];
  int tid = threadIdx.x;
  if (tid < NEXP) h[tid] = 0;
  __syncthreads();
  int e = tk_e[blockIdx.x * 256 + tid];
  atomicAdd(&h[e], 1);
  __syncthreads();
  if (tid < NEXP) blockhist[blockIdx.x * NEXP + tid] = h[tid];
}

// ---------------- scan (tp in 256-row tiles) ----------------
__global__ __launch_bounds__(512)
void k_scan2(const int* __restrict__ blockhist, int* __restrict__ counts,
             int* __restrict__ offsets, int* __restrict__ tp,
             int* __restrict__ blockbase)
{
  __shared__ int ltot[NEXP];
  __shared__ int loff[NEXP + 1];
  int tid = threadIdx.x;
  int lane = tid & 63, e = tid >> 6;
  int o0 = blockhist[lane * NEXP + e];
  int o1 = blockhist[(64 + lane) * NEXP + e];
  int h0 = o0, h1 = o1;
#pragma unroll
  for (int d = 1; d < 64; d <<= 1) { int v = __shfl_up(h0, d); if (lane >= d) h0 += v; }
  int s0 = __shfl(h0, 63);
#pragma unroll
  for (int d = 1; d < 64; d <<= 1) { int v = __shfl_up(h1, d); if (lane >= d) h1 += v; }
  h1 += s0;
  if (lane == 63) ltot[e] = h1;
  __syncthreads();
  if (tid == 0) {
    loff[0] = 0;
    int tpv = 0; tp[0] = 0;
    for (int k = 0; k < NEXP; ++k) {
      loff[k + 1] = loff[k] + ltot[k];
      counts[k] = ltot[k];
      offsets[k] = loff[k];
      tpv += (ltot[k] + 255) / 256;
      tp[k + 1] = tpv;
    }
    offsets[NEXP] = loff[NEXP];
  }
  __syncthreads();
  int base = loff[e];
  blockbase[lane * NEXP + e]        = base + h0 - o0;
  blockbase[(64 + lane) * NEXP + e] = base + h1 - o1;
}

// ---------------- stable slot assign + gather ----------------
__global__ __launch_bounds__(256)
void k_assign_gather(const float* __restrict__ x, const int* __restrict__ tk_e,
                     const float* __restrict__ tk_w,
                     const int* __restrict__ blockbase,
                     int* __restrict__ tok2slot, float* __restrict__ slot_w,
                     unsigned short* __restrict__ Xg)
{
  __shared__ int eh[256];
  __shared__ int sslot[256];
  int b = blockIdx.x, tid = threadIdx.x;
  int pick = b * 256 + tid;
  int e = tk_e[pick];
  eh[tid] = e;
  __syncthreads();
  int rank = 0;
  for (int j = 0; j < tid; ++j) rank += (eh[j] == e);
  int slot = blockbase[b * NEXP + e] + rank;
  sslot[tid] = slot;
  tok2slot[pick] = slot;          // pick = 2*token + kk
  slot_w[slot] = tk_w[pick];
  __syncthreads();
  int lane = tid & 63, wid = tid >> 6;
  for (int p = wid * 64; p < wid * 64 + 64; ++p) {
    int token = (b * 256 + p) >> 1;
    int s = sslot[p];
    const float4* src = (const float4*)(x + (size_t)token * CDIM);
    ushort4* dst = (ushort4*)(Xg + (size_t)s * CDIM);
#pragma unroll
    for (int i = 0; i < 3; ++i) {
      float4 v = src[i * 64 + lane];
      ushort4 hh;
      hh.x = f2bf(v.x); hh.y = f2bf(v.y); hh.z = f2bf(v.z); hh.w = f2bf(v.w);
      dst[i * 64 + lane] = hh;
    }
  }
}

// ============ GEMM1: 256x256 tile, BK=64, 8-phase, 512 threads ==============
// R9 schedule, compile-time KI=6 fully unrolled (R12-proven).
__global__ __launch_bounds__(512, 2)
void k_gemm1(const unsigned short* __restrict__ A, int lda,
             const unsigned short* __restrict__ B, int ldb, long sB,
             const int* __restrict__ counts,
             const int* __restrict__ offsets, const int* __restrict__ tp,
             int t0, const float* __restrict__ bias, int biasStride,
             unsigned short* __restrict__ Hout, int ldh, int gx, int nwg)
{
  constexpr int KI = CDIM / 128;   // 6 — compile-time
  __shared__ __align__(16) char lds[131072];

  int orig = blockIdx.y * gx + blockIdx.x;
  int q = nwg >> 3, r = nwg & 7;
  int xcd = orig & 7, jj = orig >> 3;
  int wgid = (xcd < r ? xcd * (q + 1) : r * (q + 1) + (xcd - r) * q) + jj;
  const int RG = 16;
  int yT = nwg / gx;
  int gsize = gx * RG;
  int rg = wgid / gsize;
  int rem = wgid - rg * gsize;
  int rgs = yT - rg * RG; if (rgs > RG) rgs = RG;
  int bx = rem / rgs;
  int byl = rg * RG + (rem - bx * rgs);
  int by = t0 + byl;

  if (by >= tp[NEXP]) return;
  int e = 0;
  while (by >= tp[e + 1]) ++e;
  int rowbase = offsets[e];
  int m0 = (by - tp[e]) * 256;
  int n0 = bx * 256;

  const unsigned short* Bexp = B + (long)e * sB + (long)n0 * ldb;
  const unsigned short* Aexp = A + (long)(rowbase + m0) * lda;

  int tid = threadIdx.x;
  int lane = tid & 63, wid = tid >> 6;
  int wm = wid >> 2, wn = wid & 3;              // 2M x 4N waves
  int ar = lane & 15, kg = lane >> 4;
  int arl = ar & 7;

  const char* pA[2][2];
  const char* pB[2][2];
#pragma unroll
  for (int d = 0; d < 2; ++d)
#pragma unroll
    for (int s = 0; s < 2; ++s) {
      int sw = (((s * 4 + kg) ^ arl) << 4);
      pA[d][s] = lds + d * 65536 + (wm * 128 + ar) * 128 + sw;
      pB[d][s] = lds + d * 65536 + 32768 + (wn * 64 + ar) * 128 + sw;
    }

  int srow = tid >> 3, schunk = tid & 7;
  int sswz = ((schunk ^ (srow & 7)) << 3);
  const unsigned short* srcA = Aexp + (long)srow * lda + sswz;
  const unsigned short* srcB = Bexp + (long)srow * ldb + sswz;

  auto STG_A = [&](int d, int kt, int g) {
    async16(srcA + (long)g * 64 * lda + kt * 64,
            lds + d * 65536 + g * 8192 + wid * 1024);
  };
  auto STG_B = [&](int d, int kt, int g) {
    async16(srcB + (long)g * 64 * ldb + kt * 64,
            lds + d * 65536 + 32768 + g * 8192 + wid * 1024);
  };

  f32x4 acc[8][4] = {};
  bf16x8 a[2][4], b[2][4];

#define LDA_(d, h)                                                   \
  _Pragma("unroll") for (int s = 0; s < 2; ++s)                      \
  _Pragma("unroll") for (int m = 0; m < 4; ++m)                      \
    a[s][m] = *(const bf16x8*)(pA[d][s] + (h) * 8192 + m * 2048);
#define LDB_(d, np)                                                  \
  _Pragma("unroll") for (int s = 0; s < 2; ++s)                      \
  _Pragma("unroll") for (int j = 0; j < 2; ++j)                      \
    b[s][(np) * 2 + j] = *(const bf16x8*)(pB[d][s] + ((np) * 2 + j) * 2048);
#define MM_(h, np)                                                   \
  _Pragma("unroll") for (int m = 0; m < 4; ++m)                      \
  _Pragma("unroll") for (int j = 0; j < 2; ++j) {                    \
    acc[(h)*4+m][(np)*2+j] = __builtin_amdgcn_mfma_f32_16x16x32_bf16(\
        a[0][m], b[0][(np)*2+j], acc[(h)*4+m][(np)*2+j], 0, 0, 0);   \
    acc[(h)*4+m][(np)*2+j] = __builtin_amdgcn_mfma_f32_16x16x32_bf16(\
        a[1][m], b[1][(np)*2+j], acc[(h)*4+m][(np)*2+j], 0, 0, 0); }
#define PHTAIL()                                                     \
  LGK0(); __builtin_amdgcn_sched_barrier(0);                         \
  __builtin_amdgcn_s_setprio(1)
#define PHEND()                                                      \
  __builtin_amdgcn_s_setprio(0); BARRIER()

  STG_A(0, 0, 0); STG_A(0, 0, 1); STG_A(0, 0, 2); STG_A(0, 0, 3);
  STG_B(0, 0, 0); STG_B(0, 0, 1); STG_B(0, 0, 2); STG_B(0, 0, 3);
  STG_A(1, 1, 0); STG_A(1, 1, 1);
  VMC(2);
  BARRIER();

#pragma unroll
  for (int i = 0; i < KI; ++i) {
    const int kt1 = 2 * i + 1, kt2 = 2 * i + 2, kt3 = 2 * i + 3;
    const bool cond = (i + 1 < KI);
    LDA_(0, 0); LDB_(0, 0);
    STG_A(1, kt1, 2); STG_A(1, kt1, 3);
    BARRIER(); PHTAIL(); MM_(0, 0); PHEND();
    LDB_(0, 1);
    STG_B(1, kt1, 0); STG_B(1, kt1, 1);
    BARRIER(); PHTAIL(); MM_(0, 1); PHEND();
    LDA_(0, 1);
    STG_B(1, kt1, 2); STG_B(1, kt1, 3);
    BARRIER(); PHTAIL(); MM_(1, 0); PHEND();
    if (cond) {
      STG_A(0, kt2, 0); STG_A(0, kt2, 1);
      VMC(2);
    } else {
      VMC(0);
    }
    BARRIER(); PHTAIL(); MM_(1, 1); PHEND();
    LDA_(1, 0); LDB_(1, 0);
    if (cond) { STG_A(0, kt2, 2); STG_A(0, kt2, 3); }
    BARRIER(); PHTAIL(); MM_(0, 0); PHEND();
    LDB_(1, 1);
    if (cond) { STG_B(0, kt2, 0); STG_B(0, kt2, 1); }
    BARRIER(); PHTAIL(); MM_(0, 1); PHEND();
    LDA_(1, 1);
    if (cond) { STG_B(0, kt2, 2); STG_B(0, kt2, 3); }
    BARRIER(); PHTAIL(); MM_(1, 0); PHEND();
    if (cond) {
      STG_A(1, kt3, 0); STG_A(1, kt3, 1);
      VMC(2);
    }
    BARRIER(); PHTAIL(); MM_(1, 1); PHEND();
  }

  unsigned short* st = (unsigned short*)lds;
  __syncthreads();
#pragma unroll
  for (int pass = 0; pass < 2; ++pass) {
    if (wm == pass) {
#pragma unroll
      for (int n = 0; n < 4; ++n) {
        int col = wn * 64 + n * 16 + ar;
        float bv = bias[e * biasStride + n0 + col];
#pragma unroll
        for (int m = 0; m < 8; ++m) {
#pragma unroll
          for (int rr = 0; rr < 4; ++rr) {
            int row = m * 16 + kg * 4 + rr;
            float v = fast_gelu(acc[m][n][rr] + bv);
            st[row * 264 + col] = f2bf(v);
          }
        }
      }
    }
    __syncthreads();
    int row = tid >> 2, qq = tid & 3;
    unsigned short* drow =
        Hout + (long)(byl * 256 + pass * 128 + row) * ldh + n0 + qq * 64;
    const unsigned short* srow2 = st + row * 264 + qq * 64;
#pragma unroll
    for (int i = 0; i < 8; ++i)
      *(u16x8*)(drow + i * 8) = *(const u16x8*)(srow2 + i * 8);
    __syncthreads();
  }
#undef LDA_
#undef LDB_
#undef MM_
#undef PHTAIL
#undef PHEND
}

// ============ GEMM2: 128x128 tile, 256 threads, 2-phase 3-ring ==============
// M indexed as halves of 256-row tiles. Yslot[slot] = bf16((acc+b2)*wt).
__global__ __launch_bounds__(256, 3)
void k_gemm2(const unsigned short* __restrict__ A, int lda,
             const unsigned short* __restrict__ B, int ldb, long sB,
             int Ksteps, const int* __restrict__ counts,
             const int* __restrict__ offsets, const int* __restrict__ tp,
             int t0, const float* __restrict__ bias, int biasStride,
             unsigned short* __restrict__ Yout, const float* __restrict__ slot_w,
             int gx, int nwg)
{
  __shared__ __align__(16) char lds[3 * 16384];

  int orig = blockIdx.y * gx + blockIdx.x;
  int q = nwg >> 3, r = nwg & 7;
  int xcd = orig & 7, jj = orig >> 3;
  int wgid = (xcd < r ? xcd * (q + 1) : r * (q + 1) + (xcd - r) * q) + jj;
  const int RG = 16;
  int yT = nwg / gx;
  int gsize = gx * RG;
  int rg = wgid / gsize;
  int rem = wgid - rg * gsize;
  int rgs = yT - rg * RG; if (rgs > RG) rgs = RG;
  int bx = rem / rgs;
  int byl = rg * RG + (rem - bx * rgs);

  int t256l = byl >> 1, half = byl & 1;
  int by = t0 + t256l;
  if (by >= tp[NEXP]) return;
  int e = 0;
  while (by >= tp[e + 1]) ++e;
  int cnt = counts[e];
  int rowbase = offsets[e];
  int m0 = (by - tp[e]) * 256 + half * 128;
  if (m0 >= cnt) return;
  int n0 = bx * 128;

  const unsigned short* Bexp = B + (long)e * sB + (long)n0 * ldb;
  const unsigned short* Aexp = A + (long)(t256l * 256 + half * 128) * lda;

  int tid = threadIdx.x;
  int lane = tid & 63, wid = tid >> 6;
  int wm = wid >> 1, wn = wid & 1;
  int ar = lane & 15, kg = lane >> 4;
  int kgs = (kg ^ ((ar >> 1) & 3)) << 4;

  int rA0 = tid >> 2;
  int cA0 = tid & 3;
  int ksw = (cA0 ^ ((rA0 >> 1) & 3)) << 3;
  const unsigned short* As0 = Aexp + (long)rA0 * lda + ksw;
  const unsigned short* As1 = Aexp + (long)(rA0 + 64) * lda + ksw;
  const unsigned short* Bs0 = Bexp + (long)rA0 * ldb + ksw;
  const unsigned short* Bs1 = Bexp + (long)(rA0 + 64) * ldb + ksw;

  f32x4 acc[4][4] = {};

  auto STAGE = [&](int buf, int t) {
    char* bb = lds + buf * 16384;
    int ko = t * 32;
    async16(As0 + ko, bb + wid * 1024);
    async16(As1 + ko, bb + 4096 + wid * 1024);
    async16(Bs0 + ko, bb + 8192 + wid * 1024);
    async16(Bs1 + ko, bb + 12288 + wid * 1024);
  };

  STAGE(0, 0); STAGE(1, 1);
  int cur = 0, nxt2 = 2;

  for (int ks = 0; ks < Ksteps; ++ks) {
    if (ks + 1 < Ksteps) {
      asm volatile("s_waitcnt vmcnt(4)" ::: "memory");
    } else {
      asm volatile("s_waitcnt vmcnt(0)" ::: "memory");
    }
    __builtin_amdgcn_s_barrier();
    asm volatile("" ::: "memory");

    const char* bb = lds + cur * 16384;
    const char* bA = bb + (wm * 64 + ar) * 64 + kgs;
    const char* bB = bb + 8192 + (wn * 64 + ar) * 64 + kgs;
    bf16x8 af[4], bfr[4];
#pragma unroll
    for (int i = 0; i < 4; ++i) af[i] = *(const bf16x8*)(bA + i * 1024);
#pragma unroll
    for (int i = 0; i < 4; ++i) bfr[i] = *(const bf16x8*)(bB + i * 1024);

    if (ks + 2 < Ksteps) STAGE(nxt2, ks + 2);

#pragma unroll
    for (int mi = 0; mi < 4; ++mi)
#pragma unroll
      for (int ni = 0; ni < 4; ++ni)
        acc[mi][ni] = __builtin_amdgcn_mfma_f32_16x16x32_bf16(af[mi], bfr[ni],
                                                              acc[mi][ni], 0, 0, 0);
    cur = (cur == 2) ? 0 : cur + 1;
    nxt2 = (nxt2 == 2) ? 0 : nxt2 + 1;
  }

  unsigned short* st = (unsigned short*)lds;
  __syncthreads();

#pragma unroll
  for (int mi = 0; mi < 4; ++mi) {
#pragma unroll
    for (int rr = 0; rr < 4; ++rr) {
      int rowl = wm * 64 + mi * 16 + kg * 4 + rr;
      float wt = (m0 + rowl < cnt) ? slot_w[rowbase + m0 + rowl] : 0.f;
#pragma unroll
      for (int ni = 0; ni < 4; ++ni) {
        int col = wn * 64 + ni * 16 + ar;
        float v = (acc[mi][ni][rr] + bias[e * biasStride + n0 + col]) * wt;
        st[rowl * 136 + col] = f2bf(v);
      }
    }
  }
  __syncthreads();
  int row = tid >> 1, hh = tid & 1;
  if (m0 + row < cnt) {
    unsigned short* drow = Yout + (long)(rowbase + m0 + row) * CDIM + n0 + hh * 64;
    const unsigned short* srow = st + row * 136 + hh * 64;
#pragma unroll
    for (int i = 0; i < 8; ++i)
      *(u16x8*)(drow + i * 8) = *(const u16x8*)(srow + i * 8);
  }
}

// ---------------- final combine: out[t] = Y[slot0] + Y[slot1] ----------------
__global__ __launch_bounds__(256)
void k_combine(const unsigned short* __restrict__ Y,
               const int* __restrict__ tok2slot, float* __restrict__ out)
{
  int t = blockIdx.x * 4 + (threadIdx.x >> 6);
  int lane = threadIdx.x & 63;
  int s0 = tok2slot[2 * t], s1 = tok2slot[2 * t + 1];
  const ushort4* y0 = (const ushort4*)(Y + (size_t)s0 * CDIM);
  const ushort4* y1 = (const ushort4*)(Y + (size_t)s1 * CDIM);
  float4* o = (float4*)(out + (size_t)t * CDIM);
#pragma unroll
  for (int i = 0; i < 3; ++i) {
    ushort4 aa = y0[i * 64 + lane];
    ushort4 bb = y1[i * 64 + lane];
    float4 rr;
    rr.x = bf2f(aa.x) + bf2f(bb.x);
    rr.y = bf2f(aa.y) + bf2f(bb.y);
    rr.z = bf2f(aa.z) + bf2f(bb.z);
    rr.w = bf2f(aa.w) + bf2f(bb.w);
    o[i * 64 + lane] = rr;
  }
}

extern "C" void kernel_launch(void* const* d_in, const int* in_sizes, int n_in,
                              void* d_out, int out_size, void* d_ws, size_t ws_size,
                              hipStream_t stream) {
  const float* x        = (const float*)d_in[0];
  const float* router_w = (const float*)d_in[1];
  const float* w1       = (const float*)d_in[2];
  const float* b1       = (const float*)d_in[3];
  const float* w2       = (const float*)d_in[4];
  const float* b2       = (const float*)d_in[5];
  float* out = (float*)d_out;

  char* ws = (char*)d_ws;
  size_t off = 0;
  auto alloc = [&](size_t bytes) -> void* {
    void* p = ws + off;
    off = (off + bytes + 255) & ~(size_t)255;
    return p;
  };
  int*   counts     = (int*)alloc(NEXP * 4);
  int*   offsets    = (int*)alloc((NEXP + 1) * 4);
  int*   tp         = (int*)alloc((NEXP + 1) * 4);
  int*   tk_e       = (int*)alloc((size_t)NSLOT * 4);
  float* tk_w       = (float*)alloc((size_t)NSLOT * 4);
  int*   blockhist  = (int*)alloc((size_t)HBLK * NEXP * 4);
  int*   blockbase  = (int*)alloc((size_t)HBLK * NEXP * 4);
  int*   tok2slot   = (int*)alloc((size_t)NSLOT * 4);
  float* slot_w     = (float*)alloc((size_t)NSLOT * 4);
  unsigned short* Yslot = (unsigned short*)alloc((size_t)NSLOT * CDIM * 2);
  unsigned short* w1t = (unsigned short*)alloc((size_t)NEXP * FDIM * CDIM * 2);
  unsigned short* w2t = (unsigned short*)alloc((size_t)NEXP * CDIM * FDIM * 2);
  unsigned short* Xg  = (unsigned short*)alloc((size_t)(NSLOT + 256) * CDIM * 2);
  // M-chunking: 3 exactly-even chunks (45+45+45 = 135) — no runt dispatch
  int TPC = 45;
  if (off + (size_t)TPC * 256 * FDIM * 2 > ws_size) TPC = 27;  // 5 chunks fb
  unsigned short* H = (unsigned short*)alloc((size_t)TPC * 256 * FDIM * 2);

  k_transpose<<<dim3(FDIM / 32, CDIM / 32, NEXP), 256, 0, stream>>>(w1, w1t, CDIM, FDIM);
  k_transpose<<<dim3(CDIM / 32, FDIM / 32, NEXP), 256, 0, stream>>>(w2, w2t, FDIM, CDIM);
  k_router<<<NTOK / 4, 256, 0, stream>>>(x, router_w, tk_e, tk_w);
  k_hist<<<HBLK, 256, 0, stream>>>(tk_e, blockhist);
  k_scan2<<<1, 512, 0, stream>>>(blockhist, counts, offsets, tp, blockbase);
  k_assign_gather<<<HBLK, 256, 0, stream>>>(x, tk_e, tk_w, blockbase,
                                            tok2slot, slot_w, Xg);

  for (int t0 = 0; t0 < MAXT256; t0 += TPC) {
    int yT = (MAXT256 - t0 < TPC) ? (MAXT256 - t0) : TPC;
    int gx1 = FDIM / 256;   // 12
    k_gemm1<<<dim3(gx1, yT), 512, 0, stream>>>(
        Xg, CDIM, w1t, CDIM, (long)FDIM * CDIM,
        counts, offsets, tp, t0, b1, FDIM, H, FDIM, gx1, gx1 * yT);
    int gx2 = CDIM / 128;   // 6
    k_gemm2<<<dim3(gx2, 2 * yT), 256, 0, stream>>>(
        H, FDIM, w2t, FDIM, (long)CDIM * FDIM, FDIM / 32,
        counts, offsets, tp, t0, b2, CDIM, Yslot, slot_w, gx2, gx2 * 2 * yT);
  }
  k_combine<<<NTOK / 4, 256, 0, stream>>>(Yslot, tok2slot, out);
}

// Round 15
// 631.093 us; speedup vs baseline: 1.1116x; 1.1116x over previous
//
#include <hip/hip_runtime.h>
#include <hip/hip_bf16.h>

#define NTOK 16384
#define CDIM 768
#define FDIM 3072
#define NEXP 8
#define NSLOT 32768   // NTOK * TOPK
#define HBLK 128      // histogram blocks (NSLOT / 256)
#define MAXT256 135   // NSLOT/256 + NEXP - 1

typedef __attribute__((ext_vector_type(8))) short bf16x8;
typedef __attribute__((ext_vector_type(4))) float f32x4;
typedef __attribute__((ext_vector_type(8))) unsigned short u16x8;

__device__ __forceinline__ unsigned short f2bf(float f) {
  unsigned int u = __float_as_uint(f);
  u += 0x7FFFu + ((u >> 16) & 1u);   // RNE
  return (unsigned short)(u >> 16);
}
__device__ __forceinline__ float bf2f(unsigned short h) {
  return __uint_as_float((unsigned int)h << 16);
}

// GELU via Page-1977 logistic approx of Phi; |err| <= ~3e-4 << bf16 ulp of H
__device__ __forceinline__ float fast_gelu(float x) {
  float x2 = x * x;
  float z = x * __builtin_fmaf(0.070565402f, x2, 1.5975981f);
  float s = __builtin_amdgcn_rcpf(1.0f + __expf(-z));
  return x * s;
}

__device__ __forceinline__ void async16(const void* g, void* l) {
  __builtin_amdgcn_global_load_lds(
      (const __attribute__((address_space(1))) unsigned int*)g,
      (__attribute__((address_space(3))) unsigned int*)l, 16, 0, 0);
}

#define BARRIER() asm volatile("s_barrier" ::: "memory")
#define LGK0()    asm volatile("s_waitcnt lgkmcnt(0)" ::: "memory")
#define VMC(n)    asm volatile("s_waitcnt vmcnt(" #n ")" ::: "memory")

// ---------------- transpose + fp32->bf16 convert ----------------
__global__ __launch_bounds__(256)
void k_transpose(const float* __restrict__ src, unsigned short* __restrict__ dst,
                 int R, int Cc)
{
  __shared__ float tle[32][33];
  int e = blockIdx.z;
  int c0 = blockIdx.x * 32, r0 = blockIdx.y * 32;
  int tx = threadIdx.x & 31, ty = threadIdx.x >> 5;
  const float* s = src + (size_t)e * R * Cc;
  unsigned short* d = dst + (size_t)e * R * Cc;
#pragma unroll
  for (int i = 0; i < 4; ++i)
    tle[ty + i * 8][tx] = s[(size_t)(r0 + ty + i * 8) * Cc + c0 + tx];
  __syncthreads();
#pragma unroll
  for (int i = 0; i < 4; ++i)
    d[(size_t)(c0 + ty + i * 8) * R + r0 + tx] = f2bf(tle[tx][ty + i * 8]);
}

// ---------------- router ----------------
__global__ __launch_bounds__(256)
void k_router(const float* __restrict__ x, const float* __restrict__ rw,
              int* __restrict__ tk_e, float* __restrict__ tk_w)
{
  __shared__ float srw[NEXP * CDIM];
  int tid = threadIdx.x;
#pragma unroll
  for (int i = 0; i < (NEXP * CDIM / 4) / 256; ++i)
    ((float4*)srw)[tid + i * 256] = ((const float4*)rw)[tid + i * 256];
  __syncthreads();
  int lane = tid & 63, wid = tid >> 6;
  int t = blockIdx.x * 4 + wid;
  float a[NEXP];
#pragma unroll
  for (int e = 0; e < NEXP; ++e) a[e] = 0.f;
  const float* xr = x + (size_t)t * CDIM;
#pragma unroll
  for (int c = 0; c < CDIM / 64; ++c) {
    float xv = xr[c * 64 + lane];
#pragma unroll
    for (int e = 0; e < NEXP; ++e) a[e] += xv * srw[e * CDIM + c * 64 + lane];
  }
#pragma unroll
  for (int e = 0; e < NEXP; ++e) {
#pragma unroll
    for (int off = 32; off; off >>= 1) a[e] += __shfl_xor(a[e], off);
  }
  if (lane == 0) {
    int i0 = 0; float l0 = a[0];
#pragma unroll
    for (int e = 1; e < NEXP; ++e) if (a[e] > l0) { l0 = a[e]; i0 = e; }
    int i1 = -1; float l1 = -1e30f;
#pragma unroll
    for (int e = 0; e < NEXP; ++e) if (e != i0 && a[e] > l1) { l1 = a[e]; i1 = e; }
    float w0 = 1.f / (1.f + expf(l1 - l0));
    tk_e[2 * t] = i0;     tk_e[2 * t + 1] = i1;
    tk_w[2 * t] = w0;     tk_w[2 * t + 1] = 1.f - w0;
  }
}

// ---------------- per-block expert histogram ----------------
__global__ __launch_bounds__(256)
void k_hist(const int* __restrict__ tk_e, int* __restrict__ blockhist)
{
  __shared__ int h[NEXP];
  int tid = threadIdx.x;
  if (tid < NEXP) h[tid] = 0;
  __syncthreads();
  int e = tk_e[blockIdx.x * 256 + tid];
  atomicAdd(&h[e], 1);
  __syncthreads();
  if (tid < NEXP) blockhist[blockIdx.x * NEXP + tid] = h[tid];
}

// ---------------- scan (tp in 256-row tiles) ----------------
__global__ __launch_bounds__(512)
void k_scan2(const int* __restrict__ blockhist, int* __restrict__ counts,
             int* __restrict__ offsets, int* __restrict__ tp,
             int* __restrict__ blockbase)
{
  __shared__ int ltot[NEXP];
  __shared__ int loff[NEXP + 1];
  int tid = threadIdx.x;
  int lane = tid & 63, e = tid >> 6;
  int o0 = blockhist[lane * NEXP + e];
  int o1 = blockhist[(64 + lane) * NEXP + e];
  int h0 = o0, h1 = o1;
#pragma unroll
  for (int d = 1; d < 64; d <<= 1) { int v = __shfl_up(h0, d); if (lane >= d) h0 += v; }
  int s0 = __shfl(h0, 63);
#pragma unroll
  for (int d = 1; d < 64; d <<= 1) { int v = __shfl_up(h1, d); if (lane >= d) h1 += v; }
  h1 += s0;
  if (lane == 63) ltot[e] = h1;
  __syncthreads();
  if (tid == 0) {
    loff[0] = 0;
    int tpv = 0; tp[0] = 0;
    for (int k = 0; k < NEXP; ++k) {
      loff[k + 1] = loff[k] + ltot[k];
      counts[k] = ltot[k];
      offsets[k] = loff[k];
      tpv += (ltot[k] + 255) / 256;
      tp[k + 1] = tpv;
    }
    offsets[NEXP] = loff[NEXP];
  }
  __syncthreads();
  int base = loff[e];
  blockbase[lane * NEXP + e]        = base + h0 - o0;
  blockbase[(64 + lane) * NEXP + e] = base + h1 - o1;
}

// ---------------- stable slot assign (rank only, no gather) ----------------
__global__ __launch_bounds__(256)
void k_assign(const int* __restrict__ tk_e, const float* __restrict__ tk_w,
              const int* __restrict__ blockbase,
              int* __restrict__ tok2slot, float* __restrict__ slot_w,
              int* __restrict__ slot_pick)
{
  __shared__ int eh[256];
  int b = blockIdx.x, tid = threadIdx.x;
  int pick = b * 256 + tid;
  int e = tk_e[pick];
  eh[tid] = e;
  __syncthreads();
  int rank = 0;
  for (int j = 0; j < tid; ++j) rank += (eh[j] == e);
  int slot = blockbase[b * NEXP + e] + rank;
  tok2slot[pick] = slot;          // pick = 2*token + kk
  slot_w[slot] = tk_w[pick];
  slot_pick[slot] = pick;
}

// ---------------- gather x rows into Xg by slot (full-GPU BW) ----------------
__global__ __launch_bounds__(256)
void k_gather(const float* __restrict__ x, const int* __restrict__ slot_pick,
              unsigned short* __restrict__ Xg)
{
  int lane = threadIdx.x & 63, w = threadIdx.x >> 6;
#pragma unroll
  for (int i = 0; i < 8; ++i) {
    int s = blockIdx.x * 32 + i * 4 + w;
    int token = slot_pick[s] >> 1;
    const float4* src = (const float4*)(x + (size_t)token * CDIM);
    ushort4* dst = (ushort4*)(Xg + (size_t)s * CDIM);
#pragma unroll
    for (int j = 0; j < 3; ++j) {
      float4 v = src[j * 64 + lane];
      ushort4 hh;
      hh.x = f2bf(v.x); hh.y = f2bf(v.y); hh.z = f2bf(v.z); hh.w = f2bf(v.w);
      dst[j * 64 + lane] = hh;
    }
  }
}

// ============ GEMM1: 256x256 tile, BK=64, 8-phase, 512 threads ==============
// R9 schedule, compile-time KI=6 fully unrolled (R12-proven).
__global__ __launch_bounds__(512, 2)
void k_gemm1(const unsigned short* __restrict__ A, int lda,
             const unsigned short* __restrict__ B, int ldb, long sB,
             const int* __restrict__ counts,
             const int* __restrict__ offsets, const int* __restrict__ tp,
             int t0, const float* __restrict__ bias, int biasStride,
             unsigned short* __restrict__ Hout, int ldh, int gx, int nwg)
{
  constexpr int KI = CDIM / 128;   // 6 — compile-time
  __shared__ __align__(16) char lds[131072];

  int orig = blockIdx.y * gx + blockIdx.x;
  int q = nwg >> 3, r = nwg & 7;
  int xcd = orig & 7, jj = orig >> 3;
  int wgid = (xcd < r ? xcd * (q + 1) : r * (q + 1) + (xcd - r) * q) + jj;
  const int RG = 16;
  int yT = nwg / gx;
  int gsize = gx * RG;
  int rg = wgid / gsize;
  int rem = wgid - rg * gsize;
  int rgs = yT - rg * RG; if (rgs > RG) rgs = RG;
  int bx = rem / rgs;
  int byl = rg * RG + (rem - bx * rgs);
  int by = t0 + byl;

  if (by >= tp[NEXP]) return;
  int e = 0;
  while (by >= tp[e + 1]) ++e;
  int rowbase = offsets[e];
  int m0 = (by - tp[e]) * 256;
  int n0 = bx * 256;

  const unsigned short* Bexp = B + (long)e * sB + (long)n0 * ldb;
  const unsigned short* Aexp = A + (long)(rowbase + m0) * lda;

  int tid = threadIdx.x;
  int lane = tid & 63, wid = tid >> 6;
  int wm = wid >> 2, wn = wid & 3;              // 2M x 4N waves
  int ar = lane & 15, kg = lane >> 4;
  int arl = ar & 7;

  const char* pA[2][2];
  const char* pB[2][2];
#pragma unroll
  for (int d = 0; d < 2; ++d)
#pragma unroll
    for (int s = 0; s < 2; ++s) {
      int sw = (((s * 4 + kg) ^ arl) << 4);
      pA[d][s] = lds + d * 65536 + (wm * 128 + ar) * 128 + sw;
      pB[d][s] = lds + d * 65536 + 32768 + (wn * 64 + ar) * 128 + sw;
    }

  int srow = tid >> 3, schunk = tid & 7;
  int sswz = ((schunk ^ (srow & 7)) << 3);
  const unsigned short* srcA = Aexp + (long)srow * lda + sswz;
  const unsigned short* srcB = Bexp + (long)srow * ldb + sswz;

  auto STG_A = [&](int d, int kt, int g) {
    async16(srcA + (long)g * 64 * lda + kt * 64,
            lds + d * 65536 + g * 8192 + wid * 1024);
  };
  auto STG_B = [&](int d, int kt, int g) {
    async16(srcB + (long)g * 64 * ldb + kt * 64,
            lds + d * 65536 + 32768 + g * 8192 + wid * 1024);
  };

  f32x4 acc[8][4] = {};
  bf16x8 a[2][4], b[2][4];

#define LDA_(d, h)                                                   \
  _Pragma("unroll") for (int s = 0; s < 2; ++s)                      \
  _Pragma("unroll") for (int m = 0; m < 4; ++m)                      \
    a[s][m] = *(const bf16x8*)(pA[d][s] + (h) * 8192 + m * 2048);
#define LDB_(d, np)                                                  \
  _Pragma("unroll") for (int s = 0; s < 2; ++s)                      \
  _Pragma("unroll") for (int j = 0; j < 2; ++j)                      \
    b[s][(np) * 2 + j] = *(const bf16x8*)(pB[d][s] + ((np) * 2 + j) * 2048);
#define MM_(h, np)                                                   \
  _Pragma("unroll") for (int m = 0; m < 4; ++m)                      \
  _Pragma("unroll") for (int j = 0; j < 2; ++j) {                    \
    acc[(h)*4+m][(np)*2+j] = __builtin_amdgcn_mfma_f32_16x16x32_bf16(\
        a[0][m], b[0][(np)*2+j], acc[(h)*4+m][(np)*2+j], 0, 0, 0);   \
    acc[(h)*4+m][(np)*2+j] = __builtin_amdgcn_mfma_f32_16x16x32_bf16(\
        a[1][m], b[1][(np)*2+j], acc[(h)*4+m][(np)*2+j], 0, 0, 0); }
#define PHTAIL()                                                     \
  LGK0(); __builtin_amdgcn_sched_barrier(0);                         \
  __builtin_amdgcn_s_setprio(1)
#define PHEND()                                                      \
  __builtin_amdgcn_s_setprio(0); BARRIER()

  STG_A(0, 0, 0); STG_A(0, 0, 1); STG_A(0, 0, 2); STG_A(0, 0, 3);
  STG_B(0, 0, 0); STG_B(0, 0, 1); STG_B(0, 0, 2); STG_B(0, 0, 3);
  STG_A(1, 1, 0); STG_A(1, 1, 1);
  VMC(2);
  BARRIER();

#pragma unroll
  for (int i = 0; i < KI; ++i) {
    const int kt1 = 2 * i + 1, kt2 = 2 * i + 2, kt3 = 2 * i + 3;
    const bool cond = (i + 1 < KI);
    LDA_(0, 0); LDB_(0, 0);
    STG_A(1, kt1, 2); STG_A(1, kt1, 3);
    BARRIER(); PHTAIL(); MM_(0, 0); PHEND();
    LDB_(0, 1);
    STG_B(1, kt1, 0); STG_B(1, kt1, 1);
    BARRIER(); PHTAIL(); MM_(0, 1); PHEND();
    LDA_(0, 1);
    STG_B(1, kt1, 2); STG_B(1, kt1, 3);
    BARRIER(); PHTAIL(); MM_(1, 0); PHEND();
    if (cond) {
      STG_A(0, kt2, 0); STG_A(0, kt2, 1);
      VMC(2);
    } else {
      VMC(0);
    }
    BARRIER(); PHTAIL(); MM_(1, 1); PHEND();
    LDA_(1, 0); LDB_(1, 0);
    if (cond) { STG_A(0, kt2, 2); STG_A(0, kt2, 3); }
    BARRIER(); PHTAIL(); MM_(0, 0); PHEND();
    LDB_(1, 1);
    if (cond) { STG_B(0, kt2, 0); STG_B(0, kt2, 1); }
    BARRIER(); PHTAIL(); MM_(0, 1); PHEND();
    LDA_(1, 1);
    if (cond) { STG_B(0, kt2, 2); STG_B(0, kt2, 3); }
    BARRIER(); PHTAIL(); MM_(1, 0); PHEND();
    if (cond) {
      STG_A(1, kt3, 0); STG_A(1, kt3, 1);
      VMC(2);
    }
    BARRIER(); PHTAIL(); MM_(1, 1); PHEND();
  }

  unsigned short* st = (unsigned short*)lds;
  __syncthreads();
#pragma unroll
  for (int pass = 0; pass < 2; ++pass) {
    if (wm == pass) {
#pragma unroll
      for (int n = 0; n < 4; ++n) {
        int col = wn * 64 + n * 16 + ar;
        float bv = bias[e * biasStride + n0 + col];
#pragma unroll
        for (int m = 0; m < 8; ++m) {
#pragma unroll
          for (int rr = 0; rr < 4; ++rr) {
            int row = m * 16 + kg * 4 + rr;
            float v = fast_gelu(acc[m][n][rr] + bv);
            st[row * 264 + col] = f2bf(v);
          }
        }
      }
    }
    __syncthreads();
    int row = tid >> 2, qq = tid & 3;
    unsigned short* drow =
        Hout + (long)(byl * 256 + pass * 128 + row) * ldh + n0 + qq * 64;
    const unsigned short* srow2 = st + row * 264 + qq * 64;
#pragma unroll
    for (int i = 0; i < 8; ++i)
      *(u16x8*)(drow + i * 8) = *(const u16x8*)(srow2 + i * 8);
    __syncthreads();
  }
#undef LDA_
#undef LDB_
#undef MM_
#undef PHTAIL
#undef PHEND
}

// ============ GEMM2 (8-phase): 256x256, BK=64, KI=24, 512 threads ===========
__global__ __launch_bounds__(512, 2)
void k_gemm2_8ph(const unsigned short* __restrict__ A, int lda,
                 const unsigned short* __restrict__ B, int ldb, long sB,
                 const int* __restrict__ counts,
                 const int* __restrict__ offsets, const int* __restrict__ tp,
                 int t0, const float* __restrict__ bias, int biasStride,
                 unsigned short* __restrict__ Yout,
                 const float* __restrict__ slot_w, int gx, int nwg)
{
  constexpr int KI = FDIM / 128;   // 24
  __shared__ __align__(16) char lds[131072];

  int orig = blockIdx.y * gx + blockIdx.x;
  int q = nwg >> 3, r = nwg & 7;
  int xcd = orig & 7, jj = orig >> 3;
  int wgid = (xcd < r ? xcd * (q + 1) : r * (q + 1) + (xcd - r) * q) + jj;
  const int RG = 16;
  int yT = nwg / gx;
  int gsize = gx * RG;
  int rg = wgid / gsize;
  int rem = wgid - rg * gsize;
  int rgs = yT - rg * RG; if (rgs > RG) rgs = RG;
  int bx = rem / rgs;
  int byl = rg * RG + (rem - bx * rgs);
  int by = t0 + byl;

  if (by >= tp[NEXP]) return;
  int e = 0;
  while (by >= tp[e + 1]) ++e;
  int cnt = counts[e];
  int rowbase = offsets[e];
  int m0 = (by - tp[e]) * 256;
  int n0 = bx * 256;

  const unsigned short* Bexp = B + (long)e * sB + (long)n0 * ldb;
  const unsigned short* Aexp = A + (long)(byl * 256) * lda;   // chunk-local H

  int tid = threadIdx.x;
  int lane = tid & 63, wid = tid >> 6;
  int wm = wid >> 2, wn = wid & 3;
  int ar = lane & 15, kg = lane >> 4;
  int arl = ar & 7;

  const char* pA[2][2];
  const char* pB[2][2];
#pragma unroll
  for (int d = 0; d < 2; ++d)
#pragma unroll
    for (int s = 0; s < 2; ++s) {
      int sw = (((s * 4 + kg) ^ arl) << 4);
      pA[d][s] = lds + d * 65536 + (wm * 128 + ar) * 128 + sw;
      pB[d][s] = lds + d * 65536 + 32768 + (wn * 64 + ar) * 128 + sw;
    }

  int srow = tid >> 3, schunk = tid & 7;
  int sswz = ((schunk ^ (srow & 7)) << 3);
  const unsigned short* srcA = Aexp + (long)srow * lda + sswz;
  const unsigned short* srcB = Bexp + (long)srow * ldb + sswz;

  auto STG_A = [&](int d, int kt, int g) {
    async16(srcA + (long)g * 64 * lda + kt * 64,
            lds + d * 65536 + g * 8192 + wid * 1024);
  };
  auto STG_B = [&](int d, int kt, int g) {
    async16(srcB + (long)g * 64 * ldb + kt * 64,
            lds + d * 65536 + 32768 + g * 8192 + wid * 1024);
  };

  f32x4 acc[8][4] = {};
  bf16x8 a[2][4], b[2][4];

#define LDA_(d, h)                                                   \
  _Pragma("unroll") for (int s = 0; s < 2; ++s)                      \
  _Pragma("unroll") for (int m = 0; m < 4; ++m)                      \
    a[s][m] = *(const bf16x8*)(pA[d][s] + (h) * 8192 + m * 2048);
#define LDB_(d, np)                                                  \
  _Pragma("unroll") for (int s = 0; s < 2; ++s)                      \
  _Pragma("unroll") for (int j = 0; j < 2; ++j)                      \
    b[s][(np) * 2 + j] = *(const bf16x8*)(pB[d][s] + ((np) * 2 + j) * 2048);
#define MM_(h, np)                                                   \
  _Pragma("unroll") for (int m = 0; m < 4; ++m)                      \
  _Pragma("unroll") for (int j = 0; j < 2; ++j) {                    \
    acc[(h)*4+m][(np)*2+j] = __builtin_amdgcn_mfma_f32_16x16x32_bf16(\
        a[0][m], b[0][(np)*2+j], acc[(h)*4+m][(np)*2+j], 0, 0, 0);   \
    acc[(h)*4+m][(np)*2+j] = __builtin_amdgcn_mfma_f32_16x16x32_bf16(\
        a[1][m], b[1][(np)*2+j], acc[(h)*4+m][(np)*2+j], 0, 0, 0); }
#define PHTAIL()                                                     \
  LGK0(); __builtin_amdgcn_sched_barrier(0);                         \
  __builtin_amdgcn_s_setprio(1)
#define PHEND()                                                      \
  __builtin_amdgcn_s_setprio(0); BARRIER()

  STG_A(0, 0, 0); STG_A(0, 0, 1); STG_A(0, 0, 2); STG_A(0, 0, 3);
  STG_B(0, 0, 0); STG_B(0, 0, 1); STG_B(0, 0, 2); STG_B(0, 0, 3);
  STG_A(1, 1, 0); STG_A(1, 1, 1);
  VMC(2);
  BARRIER();

#pragma unroll 1
  for (int i = 0; i < KI; ++i) {
    const int kt1 = 2 * i + 1, kt2 = 2 * i + 2, kt3 = 2 * i + 3;
    const bool cond = (i + 1 < KI);
    LDA_(0, 0); LDB_(0, 0);
    STG_A(1, kt1, 2); STG_A(1, kt1, 3);
    BARRIER(); PHTAIL(); MM_(0, 0); PHEND();
    LDB_(0, 1);
    STG_B(1, kt1, 0); STG_B(1, kt1, 1);
    BARRIER(); PHTAIL(); MM_(0, 1); PHEND();
    LDA_(0, 1);
    STG_B(1, kt1, 2); STG_B(1, kt1, 3);
    BARRIER(); PHTAIL(); MM_(1, 0); PHEND();
    if (cond) {
      STG_A(0, kt2, 0); STG_A(0, kt2, 1);
      VMC(2);
    } else {
      VMC(0);
    }
    BARRIER(); PHTAIL(); MM_(1, 1); PHEND();
    LDA_(1, 0); LDB_(1, 0);
    if (cond) { STG_A(0, kt2, 2); STG_A(0, kt2, 3); }
    BARRIER(); PHTAIL(); MM_(0, 0); PHEND();
    LDB_(1, 1);
    if (cond) { STG_B(0, kt2, 0); STG_B(0, kt2, 1); }
    BARRIER(); PHTAIL(); MM_(0, 1); PHEND();
    LDA_(1, 1);
    if (cond) { STG_B(0, kt2, 2); STG_B(0, kt2, 3); }
    BARRIER(); PHTAIL(); MM_(1, 0); PHEND();
    if (cond) {
      STG_A(1, kt3, 0); STG_A(1, kt3, 1);
      VMC(2);
    }
    BARRIER(); PHTAIL(); MM_(1, 1); PHEND();
  }

  unsigned short* st = (unsigned short*)lds;
  __syncthreads();
#pragma unroll
  for (int pass = 0; pass < 2; ++pass) {
    if (wm == pass) {
#pragma unroll
      for (int m = 0; m < 8; ++m) {
#pragma unroll
        for (int rr = 0; rr < 4; ++rr) {
          int row = m * 16 + kg * 4 + rr;
          int grow = m0 + pass * 128 + row;
          float wt = (grow < cnt) ? slot_w[rowbase + grow] : 0.f;
#pragma unroll
          for (int n = 0; n < 4; ++n) {
            int col = wn * 64 + n * 16 + ar;
            float v = (acc[m][n][rr] + bias[e * biasStride + n0 + col]) * wt;
            st[row * 264 + col] = f2bf(v);
          }
        }
      }
    }
    __syncthreads();
    int row = tid >> 2, qq = tid & 3;
    int grow = m0 + pass * 128 + row;
    if (grow < cnt) {
      unsigned short* drow =
          Yout + (long)(rowbase + grow) * CDIM + n0 + qq * 64;
      const unsigned short* srow2 = st + row * 264 + qq * 64;
#pragma unroll
      for (int i = 0; i < 8; ++i)
        *(u16x8*)(drow + i * 8) = *(const u16x8*)(srow2 + i * 8);
    }
    __syncthreads();
  }
#undef LDA_
#undef LDB_
#undef MM_
#undef PHTAIL
#undef PHEND
}

// ============ GEMM2 (2-phase fallback): 128x128, 256 threads ================
__global__ __launch_bounds__(256, 3)
void k_gemm2(const unsigned short* __restrict__ A, int lda,
             const unsigned short* __restrict__ B, int ldb, long sB,
             int Ksteps, const int* __restrict__ counts,
             const int* __restrict__ offsets, const int* __restrict__ tp,
             int t0, const float* __restrict__ bias, int biasStride,
             unsigned short* __restrict__ Yout, const float* __restrict__ slot_w,
             int gx, int nwg)
{
  __shared__ __align__(16) char lds[3 * 16384];

  int orig = blockIdx.y * gx + blockIdx.x;
  int q = nwg >> 3, r = nwg & 7;
  int xcd = orig & 7, jj = orig >> 3;
  int wgid = (xcd < r ? xcd * (q + 1) : r * (q + 1) + (xcd - r) * q) + jj;
  const int RG = 16;
  int yT = nwg / gx;
  int gsize = gx * RG;
  int rg = wgid / gsize;
  int rem = wgid - rg * gsize;
  int rgs = yT - rg * RG; if (rgs > RG) rgs = RG;
  int bx = rem / rgs;
  int byl = rg * RG + (rem - bx * rgs);

  int t256l = byl >> 1, half = byl & 1;
  int by = t0 + t256l;
  if (by >= tp[NEXP]) return;
  int e = 0;
  while (by >= tp[e + 1]) ++e;
  int cnt = counts[e];
  int rowbase = offsets[e];
  int m0 = (by - tp[e]) * 256 + half * 128;
  if (m0 >= cnt) return;
  int n0 = bx * 128;

  const unsigned short* Bexp = B + (long)e * sB + (long)n0 * ldb;
  const unsigned short* Aexp = A + (long)(t256l * 256 + half * 128) * lda;

  int tid = threadIdx.x;
  int lane = tid & 63, wid = tid >> 6;
  int wm = wid >> 1, wn = wid & 1;
  int ar = lane & 15, kg = lane >> 4;
  int kgs = (kg ^ ((ar >> 1) & 3)) << 4;

  int rA0 = tid >> 2;
  int cA0 = tid & 3;
  int ksw = (cA0 ^ ((rA0 >> 1) & 3)) << 3;
  const unsigned short* As0 = Aexp + (long)rA0 * lda + ksw;
  const unsigned short* As1 = Aexp + (long)(rA0 + 64) * lda + ksw;
  const unsigned short* Bs0 = Bexp + (long)rA0 * ldb + ksw;
  const unsigned short* Bs1 = Bexp + (long)(rA0 + 64) * ldb + ksw;

  f32x4 acc[4][4] = {};

  auto STAGE = [&](int buf, int t) {
    char* bb = lds + buf * 16384;
    int ko = t * 32;
    async16(As0 + ko, bb + wid * 1024);
    async16(As1 + ko, bb + 4096 + wid * 1024);
    async16(Bs0 + ko, bb + 8192 + wid * 1024);
    async16(Bs1 + ko, bb + 12288 + wid * 1024);
  };

  STAGE(0, 0); STAGE(1, 1);
  int cur = 0, nxt2 = 2;

  for (int ks = 0; ks < Ksteps; ++ks) {
    if (ks + 1 < Ksteps) {
      asm volatile("s_waitcnt vmcnt(4)" ::: "memory");
    } else {
      asm volatile("s_waitcnt vmcnt(0)" ::: "memory");
    }
    __builtin_amdgcn_s_barrier();
    asm volatile("" ::: "memory");

    const char* bb = lds + cur * 16384;
    const char* bA = bb + (wm * 64 + ar) * 64 + kgs;
    const char* bB = bb + 8192 + (wn * 64 + ar) * 64 + kgs;
    bf16x8 af[4], bfr[4];
#pragma unroll
    for (int i = 0; i < 4; ++i) af[i] = *(const bf16x8*)(bA + i * 1024);
#pragma unroll
    for (int i = 0; i < 4; ++i) bfr[i] = *(const bf16x8*)(bB + i * 1024);

    if (ks + 2 < Ksteps) STAGE(nxt2, ks + 2);

#pragma unroll
    for (int mi = 0; mi < 4; ++mi)
#pragma unroll
      for (int ni = 0; ni < 4; ++ni)
        acc[mi][ni] = __builtin_amdgcn_mfma_f32_16x16x32_bf16(af[mi], bfr[ni],
                                                              acc[mi][ni], 0, 0, 0);
    cur = (cur == 2) ? 0 : cur + 1;
    nxt2 = (nxt2 == 2) ? 0 : nxt2 + 1;
  }

  unsigned short* st = (unsigned short*)lds;
  __syncthreads();

#pragma unroll
  for (int mi = 0; mi < 4; ++mi) {
#pragma unroll
    for (int rr = 0; rr < 4; ++rr) {
      int rowl = wm * 64 + mi * 16 + kg * 4 + rr;
      float wt = (m0 + rowl < cnt) ? slot_w[rowbase + m0 + rowl] : 0.f;
#pragma unroll
      for (int ni = 0; ni < 4; ++ni) {
        int col = wn * 64 + ni * 16 + ar;
        float v = (acc[mi][ni][rr] + bias[e * biasStride + n0 + col]) * wt;
        st[rowl * 136 + col] = f2bf(v);
      }
    }
  }
  __syncthreads();
  int row = tid >> 1, hh = tid & 1;
  if (m0 + row < cnt) {
    unsigned short* drow = Yout + (long)(rowbase + m0 + row) * CDIM + n0 + hh * 64;
    const unsigned short* srow = st + row * 136 + hh * 64;
#pragma unroll
    for (int i = 0; i < 8; ++i)
      *(u16x8*)(drow + i * 8) = *(const u16x8*)(srow + i * 8);
  }
}

// ---------------- final combine: out[t] = Y[slot0] + Y[slot1] ----------------
__global__ __launch_bounds__(256)
void k_combine(const unsigned short* __restrict__ Y,
               const int* __restrict__ tok2slot, float* __restrict__ out)
{
  int t = blockIdx.x * 4 + (threadIdx.x >> 6);
  int lane = threadIdx.x & 63;
  int s0 = tok2slot[2 * t], s1 = tok2slot[2 * t + 1];
  const ushort4* y0 = (const ushort4*)(Y + (size_t)s0 * CDIM);
  const ushort4* y1 = (const ushort4*)(Y + (size_t)s1 * CDIM);
  float4* o = (float4*)(out + (size_t)t * CDIM);
#pragma unroll
  for (int i = 0; i < 3; ++i) {
    ushort4 aa = y0[i * 64 + lane];
    ushort4 bb = y1[i * 64 + lane];
    float4 rr;
    rr.x = bf2f(aa.x) + bf2f(bb.x);
    rr.y = bf2f(aa.y) + bf2f(bb.y);
    rr.z = bf2f(aa.z) + bf2f(bb.z);
    rr.w = bf2f(aa.w) + bf2f(bb.w);
    o[i * 64 + lane] = rr;
  }
}

extern "C" void kernel_launch(void* const* d_in, const int* in_sizes, int n_in,
                              void* d_out, int out_size, void* d_ws, size_t ws_size,
                              hipStream_t stream) {
  const float* x        = (const float*)d_in[0];
  const float* router_w = (const float*)d_in[1];
  const float* w1       = (const float*)d_in[2];
  const float* b1       = (const float*)d_in[3];
  const float* w2       = (const float*)d_in[4];
  const float* b2       = (const float*)d_in[5];
  float* out = (float*)d_out;

  char* ws = (char*)d_ws;
  size_t off = 0;
  auto alloc = [&](size_t bytes) -> void* {
    void* p = ws + off;
    off = (off + bytes + 255) & ~(size_t)255;
    return p;
  };
  int*   counts     = (int*)alloc(NEXP * 4);
  int*   offsets    = (int*)alloc((NEXP + 1) * 4);
  int*   tp         = (int*)alloc((NEXP + 1) * 4);
  int*   tk_e       = (int*)alloc((size_t)NSLOT * 4);
  float* tk_w       = (float*)alloc((size_t)NSLOT * 4);
  int*   blockhist  = (int*)alloc((size_t)HBLK * NEXP * 4);
  int*   blockbase  = (int*)alloc((size_t)HBLK * NEXP * 4);
  int*   tok2slot   = (int*)alloc((size_t)NSLOT * 4);
  float* slot_w     = (float*)alloc((size_t)NSLOT * 4);
  int*   slot_pick  = (int*)alloc((size_t)NSLOT * 4);
  unsigned short* Yslot = (unsigned short*)alloc((size_t)NSLOT * CDIM * 2);
  unsigned short* w1t = (unsigned short*)alloc((size_t)NEXP * FDIM * CDIM * 2);
  unsigned short* w2t = (unsigned short*)alloc((size_t)NEXP * CDIM * FDIM * 2);
  unsigned short* Xg  = (unsigned short*)alloc((size_t)(NSLOT + 256) * CDIM * 2);
  // M-chunking: prefer 2 balanced chunks (68+67) — R13-proven best
  int TPC = 68;
  if (off + (size_t)TPC * 256 * FDIM * 2 > ws_size) TPC = 42;
  if (off + (size_t)TPC * 256 * FDIM * 2 > ws_size) TPC = 21;
  bool big = (TPC == 68);
  unsigned short* H = (unsigned short*)alloc((size_t)TPC * 256 * FDIM * 2);

  k_transpose<<<dim3(FDIM / 32, CDIM / 32, NEXP), 256, 0, stream>>>(w1, w1t, CDIM, FDIM);
  k_transpose<<<dim3(CDIM / 32, FDIM / 32, NEXP), 256, 0, stream>>>(w2, w2t, FDIM, CDIM);
  k_router<<<NTOK / 4, 256, 0, stream>>>(x, router_w, tk_e, tk_w);
  k_hist<<<HBLK, 256, 0, stream>>>(tk_e, blockhist);
  k_scan2<<<1, 512, 0, stream>>>(blockhist, counts, offsets, tp, blockbase);
  k_assign<<<HBLK, 256, 0, stream>>>(tk_e, tk_w, blockbase,
                                     tok2slot, slot_w, slot_pick);
  k_gather<<<NSLOT / 32, 256, 0, stream>>>(x, slot_pick, Xg);

  for (int t0 = 0; t0 < MAXT256; t0 += TPC) {
    int yT = (MAXT256 - t0 < TPC) ? (MAXT256 - t0) : TPC;
    int gx1 = FDIM / 256;   // 12
    k_gemm1<<<dim3(gx1, yT), 512, 0, stream>>>(
        Xg, CDIM, w1t, CDIM, (long)FDIM * CDIM,
        counts, offsets, tp, t0, b1, FDIM, H, FDIM, gx1, gx1 * yT);
    if (big) {
      int gx2 = CDIM / 256;  // 3
      k_gemm2_8ph<<<dim3(gx2, yT), 512, 0, stream>>>(
          H, FDIM, w2t, FDIM, (long)CDIM * FDIM,
          counts, offsets, tp, t0, b2, CDIM, Yslot, slot_w, gx2, gx2 * yT);
    } else {
      int gx2 = CDIM / 128;  // 6
      k_gemm2<<<dim3(gx2, 2 * yT), 256, 0, stream>>>(
          H, FDIM, w2t, FDIM, (long)CDIM * FDIM, FDIM / 32,
          counts, offsets, tp, t0, b2, CDIM, Yslot, slot_w, gx2, gx2 * 2 * yT);
    }
  }
  k_combine<<<NTOK / 4, 256, 0, stream>>>(Yslot, tok2slot, out);
}

// Round 16
// 628.366 us; speedup vs baseline: 1.1164x; 1.0043x over previous
//
#include <hip/hip_runtime.h>
#include <hip/hip_bf16.h>

#define NTOK 16384
#define CDIM 768
#define FDIM 3072
#define NEXP 8
#define NSLOT 32768   // NTOK * TOPK
#define HBLK 128      // histogram blocks (NSLOT / 256)
#define MAXT256 135   // NSLOT/256 + NEXP - 1

typedef __attribute__((ext_vector_type(8))) short bf16x8;
typedef __attribute__((ext_vector_type(4))) float f32x4;
typedef __attribute__((ext_vector_type(8))) unsigned short u16x8;

__device__ __forceinline__ unsigned short f2bf(float f) {
  unsigned int u = __float_as_uint(f);
  u += 0x7FFFu + ((u >> 16) & 1u);   // RNE
  return (unsigned short)(u >> 16);
}
__device__ __forceinline__ float bf2f(unsigned short h) {
  return __uint_as_float((unsigned int)h << 16);
}

// GELU via Page-1977 logistic approx of Phi; |err| <= ~3e-4 << bf16 ulp of H
__device__ __forceinline__ float fast_gelu(float x) {
  float x2 = x * x;
  float z = x * __builtin_fmaf(0.070565402f, x2, 1.5975981f);
  float s = __builtin_amdgcn_rcpf(1.0f + __expf(-z));
  return x * s;
}

__device__ __forceinline__ void async16(const void* g, void* l) {
  __builtin_amdgcn_global_load_lds(
      (const __attribute__((address_space(1))) unsigned int*)g,
      (__attribute__((address_space(3))) unsigned int*)l, 16, 0, 0);
}

#define BARRIER() asm volatile("s_barrier" ::: "memory")
#define VMC(n)    asm volatile("s_waitcnt vmcnt(" #n ")" ::: "memory")

// ---------------- transpose + fp32->bf16 convert ----------------
__global__ __launch_bounds__(256)
void k_transpose(const float* __restrict__ src, unsigned short* __restrict__ dst,
                 int R, int Cc)
{
  __shared__ float tle[32][33];
  int e = blockIdx.z;
  int c0 = blockIdx.x * 32, r0 = blockIdx.y * 32;
  int tx = threadIdx.x & 31, ty = threadIdx.x >> 5;
  const float* s = src + (size_t)e * R * Cc;
  unsigned short* d = dst + (size_t)e * R * Cc;
#pragma unroll
  for (int i = 0; i < 4; ++i)
    tle[ty + i * 8][tx] = s[(size_t)(r0 + ty + i * 8) * Cc + c0 + tx];
  __syncthreads();
#pragma unroll
  for (int i = 0; i < 4; ++i)
    d[(size_t)(c0 + ty + i * 8) * R + r0 + tx] = f2bf(tle[tx][ty + i * 8]);
}

// ---------------- router ----------------
__global__ __launch_bounds__(256)
void k_router(const float* __restrict__ x, const float* __restrict__ rw,
              int* __restrict__ tk_e, float* __restrict__ tk_w)
{
  __shared__ float srw[NEXP * CDIM];
  int tid = threadIdx.x;
#pragma unroll
  for (int i = 0; i < (NEXP * CDIM / 4) / 256; ++i)
    ((float4*)srw)[tid + i * 256] = ((const float4*)rw)[tid + i * 256];
  __syncthreads();
  int lane = tid & 63, wid = tid >> 6;
  int t = blockIdx.x * 4 + wid;
  float a[NEXP];
#pragma unroll
  for (int e = 0; e < NEXP; ++e) a[e] = 0.f;
  const float* xr = x + (size_t)t * CDIM;
#pragma unroll
  for (int c = 0; c < CDIM / 64; ++c) {
    float xv = xr[c * 64 + lane];
#pragma unroll
    for (int e = 0; e < NEXP; ++e) a[e] += xv * srw[e * CDIM + c * 64 + lane];
  }
#pragma unroll
  for (int e = 0; e < NEXP; ++e) {
#pragma unroll
    for (int off = 32; off; off >>= 1) a[e] += __shfl_xor(a[e], off);
  }
  if (lane == 0) {
    int i0 = 0; float l0 = a[0];
#pragma unroll
    for (int e = 1; e < NEXP; ++e) if (a[e] > l0) { l0 = a[e]; i0 = e; }
    int i1 = -1; float l1 = -1e30f;
#pragma unroll
    for (int e = 0; e < NEXP; ++e) if (e != i0 && a[e] > l1) { l1 = a[e]; i1 = e; }
    float w0 = 1.f / (1.f + expf(l1 - l0));
    tk_e[2 * t] = i0;     tk_e[2 * t + 1] = i1;
    tk_w[2 * t] = w0;     tk_w[2 * t + 1] = 1.f - w0;
  }
}

// ---------------- per-block expert histogram ----------------
__global__ __launch_bounds__(256)
void k_hist(const int* __restrict__ tk_e, int* __restrict__ blockhist)
{
  __shared__ int h[NEXP];
  int tid = threadIdx.x;
  if (tid < NEXP) h[tid] = 0;
  __syncthreads();
  int e = tk_e[blockIdx.x * 256 + tid];
  atomicAdd(&h[e], 1);
  __syncthreads();
  if (tid < NEXP) blockhist[blockIdx.x * NEXP + tid] = h[tid];
}

// ---------------- scan (tp in 256-row tiles) ----------------
__global__ __launch_bounds__(512)
void k_scan2(const int* __restrict__ blockhist, int* __restrict__ counts,
             int* __restrict__ offsets, int* __restrict__ tp,
             int* __restrict__ blockbase)
{
  __shared__ int ltot[NEXP];
  __shared__ int loff[NEXP + 1];
  int tid = threadIdx.x;
  int lane = tid & 63, e = tid >> 6;
  int o0 = blockhist[lane * NEXP + e];
  int o1 = blockhist[(64 + lane) * NEXP + e];
  int h0 = o0, h1 = o1;
#pragma unroll
  for (int d = 1; d < 64; d <<= 1) { int v = __shfl_up(h0, d); if (lane >= d) h0 += v; }
  int s0 = __shfl(h0, 63);
#pragma unroll
  for (int d = 1; d < 64; d <<= 1) { int v = __shfl_up(h1, d); if (lane >= d) h1 += v; }
  h1 += s0;
  if (lane == 63) ltot[e] = h1;
  __syncthreads();
  if (tid == 0) {
    loff[0] = 0;
    int tpv = 0; tp[0] = 0;
    for (int k = 0; k < NEXP; ++k) {
      loff[k + 1] = loff[k] + ltot[k];
      counts[k] = ltot[k];
      offsets[k] = loff[k];
      tpv += (ltot[k] + 255) / 256;
      tp[k + 1] = tpv;
    }
    offsets[NEXP] = loff[NEXP];
  }
  __syncthreads();
  int base = loff[e];
  blockbase[lane * NEXP + e]        = base + h0 - o0;
  blockbase[(64 + lane) * NEXP + e] = base + h1 - o1;
}

// ---------------- stable slot assign (rank only, no gather) ----------------
__global__ __launch_bounds__(256)
void k_assign(const int* __restrict__ tk_e, const float* __restrict__ tk_w,
              const int* __restrict__ blockbase,
              int* __restrict__ tok2slot, float* __restrict__ slot_w,
              int* __restrict__ slot_pick)
{
  __shared__ int eh[256];
  int b = blockIdx.x, tid = threadIdx.x;
  int pick = b * 256 + tid;
  int e = tk_e[pick];
  eh[tid] = e;
  __syncthreads();
  int rank = 0;
  for (int j = 0; j < tid; ++j) rank += (eh[j] == e);
  int slot = blockbase[b * NEXP + e] + rank;
  tok2slot[pick] = slot;          // pick = 2*token + kk
  slot_w[slot] = tk_w[pick];
  slot_pick[slot] = pick;
}

// ---------------- gather x rows into Xg by slot (full-GPU BW) ----------------
__global__ __launch_bounds__(256)
void k_gather(const float* __restrict__ x, const int* __restrict__ slot_pick,
              unsigned short* __restrict__ Xg)
{
  int lane = threadIdx.x & 63, w = threadIdx.x >> 6;
#pragma unroll
  for (int i = 0; i < 8; ++i) {
    int s = blockIdx.x * 32 + i * 4 + w;
    int token = slot_pick[s] >> 1;
    const float4* src = (const float4*)(x + (size_t)token * CDIM);
    ushort4* dst = (ushort4*)(Xg + (size_t)s * CDIM);
#pragma unroll
    for (int j = 0; j < 3; ++j) {
      float4 v = src[j * 64 + lane];
      ushort4 hh;
      hh.x = f2bf(v.x); hh.y = f2bf(v.y); hh.z = f2bf(v.z); hh.w = f2bf(v.w);
      dst[j * 64 + lane] = hh;
    }
  }
}

// ============ GEMM1: 256x256 tile, BK=64, 8-phase, 512 threads ==============
// R9 schedule, KI=6 fully unrolled. PHASE TAIL SIMPLIFIED: no explicit
// lgkmcnt(0)/sched_barrier — compiler emits fine-grained lgkm waits (G7);
// the old full-drain+order-pin per phase was an m141-style pessimization.
__global__ __launch_bounds__(512, 2)
void k_gemm1(const unsigned short* __restrict__ A, int lda,
             const unsigned short* __restrict__ B, int ldb, long sB,
             const int* __restrict__ counts,
             const int* __restrict__ offsets, const int* __restrict__ tp,
             int t0, const float* __restrict__ bias, int biasStride,
             unsigned short* __restrict__ Hout, int ldh, int gx, int nwg)
{
  constexpr int KI = CDIM / 128;   // 6 — compile-time
  __shared__ __align__(16) char lds[131072];

  int orig = blockIdx.y * gx + blockIdx.x;
  int q = nwg >> 3, r = nwg & 7;
  int xcd = orig & 7, jj = orig >> 3;
  int wgid = (xcd < r ? xcd * (q + 1) : r * (q + 1) + (xcd - r) * q) + jj;
  const int RG = 16;
  int yT = nwg / gx;
  int gsize = gx * RG;
  int rg = wgid / gsize;
  int rem = wgid - rg * gsize;
  int rgs = yT - rg * RG; if (rgs > RG) rgs = RG;
  int bx = rem / rgs;
  int byl = rg * RG + (rem - bx * rgs);
  int by = t0 + byl;

  if (by >= tp[NEXP]) return;
  int e = 0;
  while (by >= tp[e + 1]) ++e;
  int rowbase = offsets[e];
  int m0 = (by - tp[e]) * 256;
  int n0 = bx * 256;

  const unsigned short* Bexp = B + (long)e * sB + (long)n0 * ldb;
  const unsigned short* Aexp = A + (long)(rowbase + m0) * lda;

  int tid = threadIdx.x;
  int lane = tid & 63, wid = tid >> 6;
  int wm = wid >> 2, wn = wid & 3;              // 2M x 4N waves
  int ar = lane & 15, kg = lane >> 4;
  int arl = ar & 7;

  const char* pA[2][2];
  const char* pB[2][2];
#pragma unroll
  for (int d = 0; d < 2; ++d)
#pragma unroll
    for (int s = 0; s < 2; ++s) {
      int sw = (((s * 4 + kg) ^ arl) << 4);
      pA[d][s] = lds + d * 65536 + (wm * 128 + ar) * 128 + sw;
      pB[d][s] = lds + d * 65536 + 32768 + (wn * 64 + ar) * 128 + sw;
    }

  int srow = tid >> 3, schunk = tid & 7;
  int sswz = ((schunk ^ (srow & 7)) << 3);
  const unsigned short* srcA = Aexp + (long)srow * lda + sswz;
  const unsigned short* srcB = Bexp + (long)srow * ldb + sswz;

  auto STG_A = [&](int d, int kt, int g) {
    async16(srcA + (long)g * 64 * lda + kt * 64,
            lds + d * 65536 + g * 8192 + wid * 1024);
  };
  auto STG_B = [&](int d, int kt, int g) {
    async16(srcB + (long)g * 64 * ldb + kt * 64,
            lds + d * 65536 + 32768 + g * 8192 + wid * 1024);
  };

  f32x4 acc[8][4] = {};
  bf16x8 a[2][4], b[2][4];

#define LDA_(d, h)                                                   \
  _Pragma("unroll") for (int s = 0; s < 2; ++s)                      \
  _Pragma("unroll") for (int m = 0; m < 4; ++m)                      \
    a[s][m] = *(const bf16x8*)(pA[d][s] + (h) * 8192 + m * 2048);
#define LDB_(d, np)                                                  \
  _Pragma("unroll") for (int s = 0; s < 2; ++s)                      \
  _Pragma("unroll") for (int j = 0; j < 2; ++j)                      \
    b[s][(np) * 2 + j] = *(const bf16x8*)(pB[d][s] + ((np) * 2 + j) * 2048);
#define MM_(h, np)                                                   \
  _Pragma("unroll") for (int m = 0; m < 4; ++m)                      \
  _Pragma("unroll") for (int j = 0; j < 2; ++j) {                    \
    acc[(h)*4+m][(np)*2+j] = __builtin_amdgcn_mfma_f32_16x16x32_bf16(\
        a[0][m], b[0][(np)*2+j], acc[(h)*4+m][(np)*2+j], 0, 0, 0);   \
    acc[(h)*4+m][(np)*2+j] = __builtin_amdgcn_mfma_f32_16x16x32_bf16(\
        a[1][m], b[1][(np)*2+j], acc[(h)*4+m][(np)*2+j], 0, 0, 0); }
#define PHTAIL()  __builtin_amdgcn_s_setprio(1)
#define PHEND()   __builtin_amdgcn_s_setprio(0); BARRIER()

  STG_A(0, 0, 0); STG_A(0, 0, 1); STG_A(0, 0, 2); STG_A(0, 0, 3);
  STG_B(0, 0, 0); STG_B(0, 0, 1); STG_B(0, 0, 2); STG_B(0, 0, 3);
  STG_A(1, 1, 0); STG_A(1, 1, 1);
  VMC(2);
  BARRIER();

#pragma unroll
  for (int i = 0; i < KI; ++i) {
    const int kt1 = 2 * i + 1, kt2 = 2 * i + 2, kt3 = 2 * i + 3;
    const bool cond = (i + 1 < KI);
    LDA_(0, 0); LDB_(0, 0);
    STG_A(1, kt1, 2); STG_A(1, kt1, 3);
    BARRIER(); PHTAIL(); MM_(0, 0); PHEND();
    LDB_(0, 1);
    STG_B(1, kt1, 0); STG_B(1, kt1, 1);
    BARRIER(); PHTAIL(); MM_(0, 1); PHEND();
    LDA_(0, 1);
    STG_B(1, kt1, 2); STG_B(1, kt1, 3);
    BARRIER(); PHTAIL(); MM_(1, 0); PHEND();
    if (cond) {
      STG_A(0, kt2, 0); STG_A(0, kt2, 1);
      VMC(2);
    } else {
      VMC(0);
    }
    BARRIER(); PHTAIL(); MM_(1, 1); PHEND();
    LDA_(1, 0); LDB_(1, 0);
    if (cond) { STG_A(0, kt2, 2); STG_A(0, kt2, 3); }
    BARRIER(); PHTAIL(); MM_(0, 0); PHEND();
    LDB_(1, 1);
    if (cond) { STG_B(0, kt2, 0); STG_B(0, kt2, 1); }
    BARRIER(); PHTAIL(); MM_(0, 1); PHEND();
    LDA_(1, 1);
    if (cond) { STG_B(0, kt2, 2); STG_B(0, kt2, 3); }
    BARRIER(); PHTAIL(); MM_(1, 0); PHEND();
    if (cond) {
      STG_A(1, kt3, 0); STG_A(1, kt3, 1);
      VMC(2);
    }
    BARRIER(); PHTAIL(); MM_(1, 1); PHEND();
  }

  unsigned short* st = (unsigned short*)lds;
  __syncthreads();
#pragma unroll
  for (int pass = 0; pass < 2; ++pass) {
    if (wm == pass) {
#pragma unroll
      for (int n = 0; n < 4; ++n) {
        int col = wn * 64 + n * 16 + ar;
        float bv = bias[e * biasStride + n0 + col];
#pragma unroll
        for (int m = 0; m < 8; ++m) {
#pragma unroll
          for (int rr = 0; rr < 4; ++rr) {
            int row = m * 16 + kg * 4 + rr;
            float v = fast_gelu(acc[m][n][rr] + bv);
            st[row * 264 + col] = f2bf(v);
          }
        }
      }
    }
    __syncthreads();
    int row = tid >> 2, qq = tid & 3;
    unsigned short* drow =
        Hout + (long)(byl * 256 + pass * 128 + row) * ldh + n0 + qq * 64;
    const unsigned short* srow2 = st + row * 264 + qq * 64;
#pragma unroll
    for (int i = 0; i < 8; ++i)
      *(u16x8*)(drow + i * 8) = *(const u16x8*)(srow2 + i * 8);
    __syncthreads();
  }
#undef LDA_
#undef LDB_
#undef MM_
#undef PHTAIL
#undef PHEND
}

// ============ GEMM2 (8-phase): 256x256, BK=64, KI=24, 512 threads ===========
__global__ __launch_bounds__(512, 2)
void k_gemm2_8ph(const unsigned short* __restrict__ A, int lda,
                 const unsigned short* __restrict__ B, int ldb, long sB,
                 const int* __restrict__ counts,
                 const int* __restrict__ offsets, const int* __restrict__ tp,
                 int t0, const float* __restrict__ bias, int biasStride,
                 unsigned short* __restrict__ Yout,
                 const float* __restrict__ slot_w, int gx, int nwg)
{
  constexpr int KI = FDIM / 128;   // 24
  __shared__ __align__(16) char lds[131072];

  int orig = blockIdx.y * gx + blockIdx.x;
  int q = nwg >> 3, r = nwg & 7;
  int xcd = orig & 7, jj = orig >> 3;
  int wgid = (xcd < r ? xcd * (q + 1) : r * (q + 1) + (xcd - r) * q) + jj;
  const int RG = 16;
  int yT = nwg / gx;
  int gsize = gx * RG;
  int rg = wgid / gsize;
  int rem = wgid - rg * gsize;
  int rgs = yT - rg * RG; if (rgs > RG) rgs = RG;
  int bx = rem / rgs;
  int byl = rg * RG + (rem - bx * rgs);
  int by = t0 + byl;

  if (by >= tp[NEXP]) return;
  int e = 0;
  while (by >= tp[e + 1]) ++e;
  int cnt = counts[e];
  int rowbase = offsets[e];
  int m0 = (by - tp[e]) * 256;
  int n0 = bx * 256;

  const unsigned short* Bexp = B + (long)e * sB + (long)n0 * ldb;
  const unsigned short* Aexp = A + (long)(byl * 256) * lda;   // chunk-local H

  int tid = threadIdx.x;
  int lane = tid & 63, wid = tid >> 6;
  int wm = wid >> 2, wn = wid & 3;
  int ar = lane & 15, kg = lane >> 4;
  int arl = ar & 7;

  const char* pA[2][2];
  const char* pB[2][2];
#pragma unroll
  for (int d = 0; d < 2; ++d)
#pragma unroll
    for (int s = 0; s < 2; ++s) {
      int sw = (((s * 4 + kg) ^ arl) << 4);
      pA[d][s] = lds + d * 65536 + (wm * 128 + ar) * 128 + sw;
      pB[d][s] = lds + d * 65536 + 32768 + (wn * 64 + ar) * 128 + sw;
    }

  int srow = tid >> 3, schunk = tid & 7;
  int sswz = ((schunk ^ (srow & 7)) << 3);
  const unsigned short* srcA = Aexp + (long)srow * lda + sswz;
  const unsigned short* srcB = Bexp + (long)srow * ldb + sswz;

  auto STG_A = [&](int d, int kt, int g) {
    async16(srcA + (long)g * 64 * lda + kt * 64,
            lds + d * 65536 + g * 8192 + wid * 1024);
  };
  auto STG_B = [&](int d, int kt, int g) {
    async16(srcB + (long)g * 64 * ldb + kt * 64,
            lds + d * 65536 + 32768 + g * 8192 + wid * 1024);
  };

  f32x4 acc[8][4] = {};
  bf16x8 a[2][4], b[2][4];

#define LDA_(d, h)                                                   \
  _Pragma("unroll") for (int s = 0; s < 2; ++s)                      \
  _Pragma("unroll") for (int m = 0; m < 4; ++m)                      \
    a[s][m] = *(const bf16x8*)(pA[d][s] + (h) * 8192 + m * 2048);
#define LDB_(d, np)                                                  \
  _Pragma("unroll") for (int s = 0; s < 2; ++s)                      \
  _Pragma("unroll") for (int j = 0; j < 2; ++j)                      \
    b[s][(np) * 2 + j] = *(const bf16x8*)(pB[d][s] + ((np) * 2 + j) * 2048);
#define MM_(h, np)                                                   \
  _Pragma("unroll") for (int m = 0; m < 4; ++m)                      \
  _Pragma("unroll") for (int j = 0; j < 2; ++j) {                    \
    acc[(h)*4+m][(np)*2+j] = __builtin_amdgcn_mfma_f32_16x16x32_bf16(\
        a[0][m], b[0][(np)*2+j], acc[(h)*4+m][(np)*2+j], 0, 0, 0);   \
    acc[(h)*4+m][(np)*2+j] = __builtin_amdgcn_mfma_f32_16x16x32_bf16(\
        a[1][m], b[1][(np)*2+j], acc[(h)*4+m][(np)*2+j], 0, 0, 0); }
#define PHTAIL()  __builtin_amdgcn_s_setprio(1)
#define PHEND()   __builtin_amdgcn_s_setprio(0); BARRIER()

  STG_A(0, 0, 0); STG_A(0, 0, 1); STG_A(0, 0, 2); STG_A(0, 0, 3);
  STG_B(0, 0, 0); STG_B(0, 0, 1); STG_B(0, 0, 2); STG_B(0, 0, 3);
  STG_A(1, 1, 0); STG_A(1, 1, 1);
  VMC(2);
  BARRIER();

#pragma unroll 1
  for (int i = 0; i < KI; ++i) {
    const int kt1 = 2 * i + 1, kt2 = 2 * i + 2, kt3 = 2 * i + 3;
    const bool cond = (i + 1 < KI);
    LDA_(0, 0); LDB_(0, 0);
    STG_A(1, kt1, 2); STG_A(1, kt1, 3);
    BARRIER(); PHTAIL(); MM_(0, 0); PHEND();
    LDB_(0, 1);
    STG_B(1, kt1, 0); STG_B(1, kt1, 1);
    BARRIER(); PHTAIL(); MM_(0, 1); PHEND();
    LDA_(0, 1);
    STG_B(1, kt1, 2); STG_B(1, kt1, 3);
    BARRIER(); PHTAIL(); MM_(1, 0); PHEND();
    if (cond) {
      STG_A(0, kt2, 0); STG_A(0, kt2, 1);
      VMC(2);
    } else {
      VMC(0);
    }
    BARRIER(); PHTAIL(); MM_(1, 1); PHEND();
    LDA_(1, 0); LDB_(1, 0);
    if (cond) { STG_A(0, kt2, 2); STG_A(0, kt2, 3); }
    BARRIER(); PHTAIL(); MM_(0, 0); PHEND();
    LDB_(1, 1);
    if (cond) { STG_B(0, kt2, 0); STG_B(0, kt2, 1); }
    BARRIER(); PHTAIL(); MM_(0, 1); PHEND();
    LDA_(1, 1);
    if (cond) { STG_B(0, kt2, 2); STG_B(0, kt2, 3); }
    BARRIER(); PHTAIL(); MM_(1, 0); PHEND();
    if (cond) {
      STG_A(1, kt3, 0); STG_A(1, kt3, 1);
      VMC(2);
    }
    BARRIER(); PHTAIL(); MM_(1, 1); PHEND();
  }

  unsigned short* st = (unsigned short*)lds;
  __syncthreads();
#pragma unroll
  for (int pass = 0; pass < 2; ++pass) {
    if (wm == pass) {
#pragma unroll
      for (int m = 0; m < 8; ++m) {
#pragma unroll
        for (int rr = 0; rr < 4; ++rr) {
          int row = m * 16 + kg * 4 + rr;
          int grow = m0 + pass * 128 + row;
          float wt = (grow < cnt) ? slot_w[rowbase + grow] : 0.f;
#pragma unroll
          for (int n = 0; n < 4; ++n) {
            int col = wn * 64 + n * 16 + ar;
            float v = (acc[m][n][rr] + bias[e * biasStride + n0 + col]) * wt;
            st[row * 264 + col] = f2bf(v);
          }
        }
      }
    }
    __syncthreads();
    int row = tid >> 2, qq = tid & 3;
    int grow = m0 + pass * 128 + row;
    if (grow < cnt) {
      unsigned short* drow =
          Yout + (long)(rowbase + grow) * CDIM + n0 + qq * 64;
      const unsigned short* srow2 = st + row * 264 + qq * 64;
#pragma unroll
      for (int i = 0; i < 8; ++i)
        *(u16x8*)(drow + i * 8) = *(const u16x8*)(srow2 + i * 8);
    }
    __syncthreads();
  }
#undef LDA_
#undef LDB_
#undef MM_
#undef PHTAIL
#undef PHEND
}

// ============ GEMM2 (2-phase fallback): 128x128, 256 threads ================
__global__ __launch_bounds__(256, 3)
void k_gemm2(const unsigned short* __restrict__ A, int lda,
             const unsigned short* __restrict__ B, int ldb, long sB,
             int Ksteps, const int* __restrict__ counts,
             const int* __restrict__ offsets, const int* __restrict__ tp,
             int t0, const float* __restrict__ bias, int biasStride,
             unsigned short* __restrict__ Yout, const float* __restrict__ slot_w,
             int gx, int nwg)
{
  __shared__ __align__(16) char lds[3 * 16384];

  int orig = blockIdx.y * gx + blockIdx.x;
  int q = nwg >> 3, r = nwg & 7;
  int xcd = orig & 7, jj = orig >> 3;
  int wgid = (xcd < r ? xcd * (q + 1) : r * (q + 1) + (xcd - r) * q) + jj;
  const int RG = 16;
  int yT = nwg / gx;
  int gsize = gx * RG;
  int rg = wgid / gsize;
  int rem = wgid - rg * gsize;
  int rgs = yT - rg * RG; if (rgs > RG) rgs = RG;
  int bx = rem / rgs;
  int byl = rg * RG + (rem - bx * rgs);

  int t256l = byl >> 1, half = byl & 1;
  int by = t0 + t256l;
  if (by >= tp[NEXP]) return;
  int e = 0;
  while (by >= tp[e + 1]) ++e;
  int cnt = counts[e];
  int rowbase = offsets[e];
  int m0 = (by - tp[e]) * 256 + half * 128;
  if (m0 >= cnt) return;
  int n0 = bx * 128;

  const unsigned short* Bexp = B + (long)e * sB + (long)n0 * ldb;
  const unsigned short* Aexp = A + (long)(t256l * 256 + half * 128) * lda;

  int tid = threadIdx.x;
  int lane = tid & 63, wid = tid >> 6;
  int wm = wid >> 1, wn = wid & 1;
  int ar = lane & 15, kg = lane >> 4;
  int kgs = (kg ^ ((ar >> 1) & 3)) << 4;

  int rA0 = tid >> 2;
  int cA0 = tid & 3;
  int ksw = (cA0 ^ ((rA0 >> 1) & 3)) << 3;
  const unsigned short* As0 = Aexp + (long)rA0 * lda + ksw;
  const unsigned short* As1 = Aexp + (long)(rA0 + 64) * lda + ksw;
  const unsigned short* Bs0 = Bexp + (long)rA0 * ldb + ksw;
  const unsigned short* Bs1 = Bexp + (long)(rA0 + 64) * ldb + ksw;

  f32x4 acc[4][4] = {};

  auto STAGE = [&](int buf, int t) {
    char* bb = lds + buf * 16384;
    int ko = t * 32;
    async16(As0 + ko, bb + wid * 1024);
    async16(As1 + ko, bb + 4096 + wid * 1024);
    async16(Bs0 + ko, bb + 8192 + wid * 1024);
    async16(Bs1 + ko, bb + 12288 + wid * 1024);
  };

  STAGE(0, 0); STAGE(1, 1);
  int cur = 0, nxt2 = 2;

  for (int ks = 0; ks < Ksteps; ++ks) {
    if (ks + 1 < Ksteps) {
      asm volatile("s_waitcnt vmcnt(4)" ::: "memory");
    } else {
      asm volatile("s_waitcnt vmcnt(0)" ::: "memory");
    }
    __builtin_amdgcn_s_barrier();
    asm volatile("" ::: "memory");

    const char* bb = lds + cur * 16384;
    const char* bA = bb + (wm * 64 + ar) * 64 + kgs;
    const char* bB = bb + 8192 + (wn * 64 + ar) * 64 + kgs;
    bf16x8 af[4], bfr[4];
#pragma unroll
    for (int i = 0; i < 4; ++i) af[i] = *(const bf16x8*)(bA + i * 1024);
#pragma unroll
    for (int i = 0; i < 4; ++i) bfr[i] = *(const bf16x8*)(bB + i * 1024);

    if (ks + 2 < Ksteps) STAGE(nxt2, ks + 2);

#pragma unroll
    for (int mi = 0; mi < 4; ++mi)
#pragma unroll
      for (int ni = 0; ni < 4; ++ni)
        acc[mi][ni] = __builtin_amdgcn_mfma_f32_16x16x32_bf16(af[mi], bfr[ni],
                                                              acc[mi][ni], 0, 0, 0);
    cur = (cur == 2) ? 0 : cur + 1;
    nxt2 = (nxt2 == 2) ? 0 : nxt2 + 1;
  }

  unsigned short* st = (unsigned short*)lds;
  __syncthreads();

#pragma unroll
  for (int mi = 0; mi < 4; ++mi) {
#pragma unroll
    for (int rr = 0; rr < 4; ++rr) {
      int rowl = wm * 64 + mi * 16 + kg * 4 + rr;
      float wt = (m0 + rowl < cnt) ? slot_w[rowbase + m0 + rowl] : 0.f;
#pragma unroll
      for (int ni = 0; ni < 4; ++ni) {
        int col = wn * 64 + ni * 16 + ar;
        float v = (acc[mi][ni][rr] + bias[e * biasStride + n0 + col]) * wt;
        st[rowl * 136 + col] = f2bf(v);
      }
    }
  }
  __syncthreads();
  int row = tid >> 1, hh = tid & 1;
  if (m0 + row < cnt) {
    unsigned short* drow = Yout + (long)(rowbase + m0 + row) * CDIM + n0 + hh * 64;
    const unsigned short* srow = st + row * 136 + hh * 64;
#pragma unroll
    for (int i = 0; i < 8; ++i)
      *(u16x8*)(drow + i * 8) = *(const u16x8*)(srow + i * 8);
  }
}

// ---------------- final combine: out[t] = Y[slot0] + Y[slot1] ----------------
__global__ __launch_bounds__(256)
void k_combine(const unsigned short* __restrict__ Y,
               const int* __restrict__ tok2slot, float* __restrict__ out)
{
  int t = blockIdx.x * 4 + (threadIdx.x >> 6);
  int lane = threadIdx.x & 63;
  int s0 = tok2slot[2 * t], s1 = tok2slot[2 * t + 1];
  const ushort4* y0 = (const ushort4*)(Y + (size_t)s0 * CDIM);
  const ushort4* y1 = (const ushort4*)(Y + (size_t)s1 * CDIM);
  float4* o = (float4*)(out + (size_t)t * CDIM);
#pragma unroll
  for (int i = 0; i < 3; ++i) {
    ushort4 aa = y0[i * 64 + lane];
    ushort4 bb = y1[i * 64 + lane];
    float4 rr;
    rr.x = bf2f(aa.x) + bf2f(bb.x);
    rr.y = bf2f(aa.y) + bf2f(bb.y);
    rr.z = bf2f(aa.z) + bf2f(bb.z);
    rr.w = bf2f(aa.w) + bf2f(bb.w);
    o[i * 64 + lane] = rr;
  }
}

extern "C" void kernel_launch(void* const* d_in, const int* in_sizes, int n_in,
                              void* d_out, int out_size, void* d_ws, size_t ws_size,
                              hipStream_t stream) {
  const float* x        = (const float*)d_in[0];
  const float* router_w = (const float*)d_in[1];
  const float* w1       = (const float*)d_in[2];
  const float* b1       = (const float*)d_in[3];
  const float* w2       = (const float*)d_in[4];
  const float* b2       = (const float*)d_in[5];
  float* out = (float*)d_out;

  char* ws = (char*)d_ws;
  size_t off = 0;
  auto alloc = [&](size_t bytes) -> void* {
    void* p = ws + off;
    off = (off + bytes + 255) & ~(size_t)255;
    return p;
  };
  int*   counts     = (int*)alloc(NEXP * 4);
  int*   offsets    = (int*)alloc((NEXP + 1) * 4);
  int*   tp         = (int*)alloc((NEXP + 1) * 4);
  int*   tk_e       = (int*)alloc((size_t)NSLOT * 4);
  float* tk_w       = (float*)alloc((size_t)NSLOT * 4);
  int*   blockhist  = (int*)alloc((size_t)HBLK * NEXP * 4);
  int*   blockbase  = (int*)alloc((size_t)HBLK * NEXP * 4);
  int*   tok2slot   = (int*)alloc((size_t)NSLOT * 4);
  float* slot_w     = (float*)alloc((size_t)NSLOT * 4);
  int*   slot_pick  = (int*)alloc((size_t)NSLOT * 4);
  unsigned short* Yslot = (unsigned short*)alloc((size_t)NSLOT * CDIM * 2);
  unsigned short* w1t = (unsigned short*)alloc((size_t)NEXP * FDIM * CDIM * 2);
  unsigned short* w2t = (unsigned short*)alloc((size_t)NEXP * CDIM * FDIM * 2);
  unsigned short* Xg  = (unsigned short*)alloc((size_t)(NSLOT + 256) * CDIM * 2);
  // M-chunking: prefer 2 balanced chunks (68+67) — R13-proven best
  int TPC = 68;
  if (off + (size_t)TPC * 256 * FDIM * 2 > ws_size) TPC = 42;
  if (off + (size_t)TPC * 256 * FDIM * 2 > ws_size) TPC = 21;
  bool big = (TPC == 68);
  unsigned short* H = (unsigned short*)alloc((size_t)TPC * 256 * FDIM * 2);

  k_transpose<<<dim3(FDIM / 32, CDIM / 32, NEXP), 256, 0, stream>>>(w1, w1t, CDIM, FDIM);
  k_transpose<<<dim3(CDIM / 32, FDIM / 32, NEXP), 256, 0, stream>>>(w2, w2t, FDIM, CDIM);
  k_router<<<NTOK / 4, 256, 0, stream>>>(x, router_w, tk_e, tk_w);
  k_hist<<<HBLK, 256, 0, stream>>>(tk_e, blockhist);
  k_scan2<<<1, 512, 0, stream>>>(blockhist, counts, offsets, tp, blockbase);
  k_assign<<<HBLK, 256, 0, stream>>>(tk_e, tk_w, blockbase,
                                     tok2slot, slot_w, slot_pick);
  k_gather<<<NSLOT / 32, 256, 0, stream>>>(x, slot_pick, Xg);

  for (int t0 = 0; t0 < MAXT256; t0 += TPC) {
    int yT = (MAXT256 - t0 < TPC) ? (MAXT256 - t0) : TPC;
    int gx1 = FDIM / 256;   // 12
    k_gemm1<<<dim3(gx1, yT), 512, 0, stream>>>(
        Xg, CDIM, w1t, CDIM, (long)FDIM * CDIM,
        counts, offsets, tp, t0, b1, FDIM, H, FDIM, gx1, gx1 * yT);
    if (big) {
      int gx2 = CDIM / 256;  // 3
      k_gemm2_8ph<<<dim3(gx2, yT), 512, 0, stream>>>(
          H, FDIM, w2t, FDIM, (long)CDIM * FDIM,
          counts, offsets, tp, t0, b2, CDIM, Yslot, slot_w, gx2, gx2 * yT);
    } else {
      int gx2 = CDIM / 128;  // 6
      k_gemm2<<<dim3(gx2, 2 * yT), 256, 0, stream>>>(
          H, FDIM, w2t, FDIM, (long)CDIM * FDIM, FDIM / 32,
          counts, offsets, tp, t0, b2, CDIM, Yslot, slot_w, gx2, gx2 * 2 * yT);
    }
  }
  k_combine<<<NTOK / 4, 256, 0, stream>>>(Yslot, tok2slot, out);
}

// Round 17
// 619.812 us; speedup vs baseline: 1.1318x; 1.0138x over previous
//
#include <hip/hip_runtime.h>
#include <hip/hip_bf16.h>

#define NTOK 16384
#define CDIM 768
#define FDIM 3072
#define NEXP 8
#define NSLOT 32768   // NTOK * TOPK
#define HBLK 128      // histogram blocks (NSLOT / 256)
#define MAXT256 135   // NSLOT/256 + NEXP - 1

typedef __attribute__((ext_vector_type(8))) short bf16x8;
typedef __attribute__((ext_vector_type(4))) float f32x4;
typedef __attribute__((ext_vector_type(8))) unsigned short u16x8;

__device__ __forceinline__ unsigned short f2bf(float f) {
  unsigned int u = __float_as_uint(f);
  u += 0x7FFFu + ((u >> 16) & 1u);   // RNE
  return (unsigned short)(u >> 16);
}
__device__ __forceinline__ float bf2f(unsigned short h) {
  return __uint_as_float((unsigned int)h << 16);
}

// GELU via Page-1977 logistic approx of Phi; |err| <= ~3e-4 << bf16 ulp of H
__device__ __forceinline__ float fast_gelu(float x) {
  float x2 = x * x;
  float z = x * __builtin_fmaf(0.070565402f, x2, 1.5975981f);
  float s = __builtin_amdgcn_rcpf(1.0f + __expf(-z));
  return x * s;
}

__device__ __forceinline__ void async16(const void* g, void* l) {
  __builtin_amdgcn_global_load_lds(
      (const __attribute__((address_space(1))) unsigned int*)g,
      (__attribute__((address_space(3))) unsigned int*)l, 16, 0, 0);
}

#define BARRIER() asm volatile("s_barrier" ::: "memory")
#define VMC(n)    asm volatile("s_waitcnt vmcnt(" #n ")" ::: "memory")

// ---------------- transpose + fp32->bf16 convert ----------------
__global__ __launch_bounds__(256)
void k_transpose(const float* __restrict__ src, unsigned short* __restrict__ dst,
                 int R, int Cc)
{
  __shared__ float tle[32][33];
  int e = blockIdx.z;
  int c0 = blockIdx.x * 32, r0 = blockIdx.y * 32;
  int tx = threadIdx.x & 31, ty = threadIdx.x >> 5;
  const float* s = src + (size_t)e * R * Cc;
  unsigned short* d = dst + (size_t)e * R * Cc;
#pragma unroll
  for (int i = 0; i < 4; ++i)
    tle[ty + i * 8][tx] = s[(size_t)(r0 + ty + i * 8) * Cc + c0 + tx];
  __syncthreads();
#pragma unroll
  for (int i = 0; i < 4; ++i)
    d[(size_t)(c0 + ty + i * 8) * R + r0 + tx] = f2bf(tle[tx][ty + i * 8]);
}

// ---------------- dense x -> bf16 copy (replaces gather) ----------------
__global__ __launch_bounds__(256)
void k_xbf16(const float* __restrict__ x, unsigned short* __restrict__ Xbf)
{
  size_t i = (size_t)blockIdx.x * 256 + threadIdx.x;
  const float4* s = (const float4*)x;
  float4 v0 = s[2 * i], v1 = s[2 * i + 1];
  u16x8 h;
  h[0] = f2bf(v0.x); h[1] = f2bf(v0.y); h[2] = f2bf(v0.z); h[3] = f2bf(v0.w);
  h[4] = f2bf(v1.x); h[5] = f2bf(v1.y); h[6] = f2bf(v1.z); h[7] = f2bf(v1.w);
  ((u16x8*)Xbf)[i] = h;
}

// ---------------- router ----------------
__global__ __launch_bounds__(256)
void k_router(const float* __restrict__ x, const float* __restrict__ rw,
              int* __restrict__ tk_e, float* __restrict__ tk_w)
{
  __shared__ float srw[NEXP * CDIM];
  int tid = threadIdx.x;
#pragma unroll
  for (int i = 0; i < (NEXP * CDIM / 4) / 256; ++i)
    ((float4*)srw)[tid + i * 256] = ((const float4*)rw)[tid + i * 256];
  __syncthreads();
  int lane = tid & 63, wid = tid >> 6;
  int t = blockIdx.x * 4 + wid;
  float a[NEXP];
#pragma unroll
  for (int e = 0; e < NEXP; ++e) a[e] = 0.f;
  const float* xr = x + (size_t)t * CDIM;
#pragma unroll
  for (int c = 0; c < CDIM / 64; ++c) {
    float xv = xr[c * 64 + lane];
#pragma unroll
    for (int e = 0; e < NEXP; ++e) a[e] += xv * srw[e * CDIM + c * 64 + lane];
  }
#pragma unroll
  for (int e = 0; e < NEXP; ++e) {
#pragma unroll
    for (int off = 32; off; off >>= 1) a[e] += __shfl_xor(a[e], off);
  }
  if (lane == 0) {
    int i0 = 0; float l0 = a[0];
#pragma unroll
    for (int e = 1; e < NEXP; ++e) if (a[e] > l0) { l0 = a[e]; i0 = e; }
    int i1 = -1; float l1 = -1e30f;
#pragma unroll
    for (int e = 0; e < NEXP; ++e) if (e != i0 && a[e] > l1) { l1 = a[e]; i1 = e; }
    float w0 = 1.f / (1.f + expf(l1 - l0));
    tk_e[2 * t] = i0;     tk_e[2 * t + 1] = i1;
    tk_w[2 * t] = w0;     tk_w[2 * t + 1] = 1.f - w0;
  }
}

// ---------------- per-block expert histogram ----------------
__global__ __launch_bounds__(256)
void k_hist(const int* __restrict__ tk_e, int* __restrict__ blockhist)
{
  __shared__ int h[NEXP];
  int tid = threadIdx.x;
  if (tid < NEXP) h[tid] = 0;
  __syncthreads();
  int e = tk_e[blockIdx.x * 256 + tid];
  atomicAdd(&h[e], 1);
  __syncthreads();
  if (tid < NEXP) blockhist[blockIdx.x * NEXP + tid] = h[tid];
}

// ---------------- scan (tp in 256-row tiles) ----------------
__global__ __launch_bounds__(512)
void k_scan2(const int* __restrict__ blockhist, int* __restrict__ counts,
             int* __restrict__ offsets, int* __restrict__ tp,
             int* __restrict__ blockbase)
{
  __shared__ int ltot[NEXP];
  __shared__ int loff[NEXP + 1];
  int tid = threadIdx.x;
  int lane = tid & 63, e = tid >> 6;
  int o0 = blockhist[lane * NEXP + e];
  int o1 = blockhist[(64 + lane) * NEXP + e];
  int h0 = o0, h1 = o1;
#pragma unroll
  for (int d = 1; d < 64; d <<= 1) { int v = __shfl_up(h0, d); if (lane >= d) h0 += v; }
  int s0 = __shfl(h0, 63);
#pragma unroll
  for (int d = 1; d < 64; d <<= 1) { int v = __shfl_up(h1, d); if (lane >= d) h1 += v; }
  h1 += s0;
  if (lane == 63) ltot[e] = h1;
  __syncthreads();
  if (tid == 0) {
    loff[0] = 0;
    int tpv = 0; tp[0] = 0;
    for (int k = 0; k < NEXP; ++k) {
      loff[k + 1] = loff[k] + ltot[k];
      counts[k] = ltot[k];
      offsets[k] = loff[k];
      tpv += (ltot[k] + 255) / 256;
      tp[k + 1] = tpv;
    }
    offsets[NEXP] = loff[NEXP];
  }
  __syncthreads();
  int base = loff[e];
  blockbase[lane * NEXP + e]        = base + h0 - o0;
  blockbase[(64 + lane) * NEXP + e] = base + h1 - o1;
}

// ---------------- stable slot assign ----------------
__global__ __launch_bounds__(256)
void k_assign(const int* __restrict__ tk_e, const float* __restrict__ tk_w,
              const int* __restrict__ blockbase,
              int* __restrict__ tok2slot, float* __restrict__ slot_w,
              int* __restrict__ slot_pick)
{
  __shared__ int eh[256];
  int b = blockIdx.x, tid = threadIdx.x;
  int pick = b * 256 + tid;
  int e = tk_e[pick];
  eh[tid] = e;
  __syncthreads();
  int rank = 0;
  for (int j = 0; j < tid; ++j) rank += (eh[j] == e);
  int slot = blockbase[b * NEXP + e] + rank;
  tok2slot[pick] = slot;          // pick = 2*token + kk
  slot_w[slot] = tk_w[pick];
  slot_pick[slot] = pick;
}

// ============ GEMM1: 256x256 tile, BK=64, 8-phase, 512 threads ==============
// A staged DIRECTLY from dense Xbf via per-lane gathered global addresses
// (slot_pick row->token resolved once per thread; global_load_lds src is
// per-lane, LDS dest stays linear). No Xg buffer, no gather pass.
__global__ __launch_bounds__(512, 2)
void k_gemm1(const unsigned short* __restrict__ Xbf,
             const int* __restrict__ slot_pick,
             const unsigned short* __restrict__ B, int ldb, long sB,
             const int* __restrict__ counts,
             const int* __restrict__ offsets, const int* __restrict__ tp,
             int t0, const float* __restrict__ bias, int biasStride,
             unsigned short* __restrict__ Hout, int ldh, int gx, int nwg)
{
  constexpr int KI = CDIM / 128;   // 6 — compile-time
  __shared__ __align__(16) char lds[131072];

  int orig = blockIdx.y * gx + blockIdx.x;
  int q = nwg >> 3, r = nwg & 7;
  int xcd = orig & 7, jj = orig >> 3;
  int wgid = (xcd < r ? xcd * (q + 1) : r * (q + 1) + (xcd - r) * q) + jj;
  const int RG = 16;
  int yT = nwg / gx;
  int gsize = gx * RG;
  int rg = wgid / gsize;
  int rem = wgid - rg * gsize;
  int rgs = yT - rg * RG; if (rgs > RG) rgs = RG;
  int bx = rem / rgs;
  int byl = rg * RG + (rem - bx * rgs);
  int by = t0 + byl;

  if (by >= tp[NEXP]) return;
  int e = 0;
  while (by >= tp[e + 1]) ++e;
  int rowbase = offsets[e];
  int m0 = (by - tp[e]) * 256;
  int n0 = bx * 256;

  const unsigned short* Bexp = B + (long)e * sB + (long)n0 * ldb;

  int tid = threadIdx.x;
  int lane = tid & 63, wid = tid >> 6;
  int wm = wid >> 2, wn = wid & 3;              // 2M x 4N waves
  int ar = lane & 15, kg = lane >> 4;
  int arl = ar & 7;

  const char* pA[2][2];
  const char* pB[2][2];
#pragma unroll
  for (int d = 0; d < 2; ++d)
#pragma unroll
    for (int s = 0; s < 2; ++s) {
      int sw = (((s * 4 + kg) ^ arl) << 4);
      pA[d][s] = lds + d * 65536 + (wm * 128 + ar) * 128 + sw;
      pB[d][s] = lds + d * 65536 + 32768 + (wn * 64 + ar) * 128 + sw;
    }

  int srow = tid >> 3, schunk = tid & 7;
  int sswz = ((schunk ^ (srow & 7)) << 3);
  // resolve this thread's 4 source rows (tokens) once
  const unsigned short* srcAg[4];
#pragma unroll
  for (int g = 0; g < 4; ++g) {
    int sidx = rowbase + m0 + srow + g * 64;
    if (sidx > NSLOT - 1) sidx = NSLOT - 1;
    int tok = slot_pick[sidx] >> 1;
    srcAg[g] = Xbf + (long)tok * CDIM + sswz;
  }
  const unsigned short* srcB = Bexp + (long)srow * ldb + sswz;

  auto STG_A = [&](int d, int kt, int g) {
    async16(srcAg[g] + kt * 64,
            lds + d * 65536 + g * 8192 + wid * 1024);
  };
  auto STG_B = [&](int d, int kt, int g) {
    async16(srcB + (long)g * 64 * ldb + kt * 64,
            lds + d * 65536 + 32768 + g * 8192 + wid * 1024);
  };

  f32x4 acc[8][4] = {};
  bf16x8 a[2][4], b[2][4];

#define LDA_(d, h)                                                   \
  _Pragma("unroll") for (int s = 0; s < 2; ++s)                      \
  _Pragma("unroll") for (int m = 0; m < 4; ++m)                      \
    a[s][m] = *(const bf16x8*)(pA[d][s] + (h) * 8192 + m * 2048);
#define LDB_(d, np)                                                  \
  _Pragma("unroll") for (int s = 0; s < 2; ++s)                      \
  _Pragma("unroll") for (int j = 0; j < 2; ++j)                      \
    b[s][(np) * 2 + j] = *(const bf16x8*)(pB[d][s] + ((np) * 2 + j) * 2048);
#define MM_(h, np)                                                   \
  _Pragma("unroll") for (int m = 0; m < 4; ++m)                      \
  _Pragma("unroll") for (int j = 0; j < 2; ++j) {                    \
    acc[(h)*4+m][(np)*2+j] = __builtin_amdgcn_mfma_f32_16x16x32_bf16(\
        a[0][m], b[0][(np)*2+j], acc[(h)*4+m][(np)*2+j], 0, 0, 0);   \
    acc[(h)*4+m][(np)*2+j] = __builtin_amdgcn_mfma_f32_16x16x32_bf16(\
        a[1][m], b[1][(np)*2+j], acc[(h)*4+m][(np)*2+j], 0, 0, 0); }
#define PHTAIL()  __builtin_amdgcn_s_setprio(1)
#define PHEND()   __builtin_amdgcn_s_setprio(0); BARRIER()

  STG_A(0, 0, 0); STG_A(0, 0, 1); STG_A(0, 0, 2); STG_A(0, 0, 3);
  STG_B(0, 0, 0); STG_B(0, 0, 1); STG_B(0, 0, 2); STG_B(0, 0, 3);
  STG_A(1, 1, 0); STG_A(1, 1, 1);
  VMC(2);
  BARRIER();

#pragma unroll
  for (int i = 0; i < KI; ++i) {
    const int kt1 = 2 * i + 1, kt2 = 2 * i + 2, kt3 = 2 * i + 3;
    const bool cond = (i + 1 < KI);
    LDA_(0, 0); LDB_(0, 0);
    STG_A(1, kt1, 2); STG_A(1, kt1, 3);
    BARRIER(); PHTAIL(); MM_(0, 0); PHEND();
    LDB_(0, 1);
    STG_B(1, kt1, 0); STG_B(1, kt1, 1);
    BARRIER(); PHTAIL(); MM_(0, 1); PHEND();
    LDA_(0, 1);
    STG_B(1, kt1, 2); STG_B(1, kt1, 3);
    BARRIER(); PHTAIL(); MM_(1, 0); PHEND();
    if (cond) {
      STG_A(0, kt2, 0); STG_A(0, kt2, 1);
      VMC(2);
    } else {
      VMC(0);
    }
    BARRIER(); PHTAIL(); MM_(1, 1); PHEND();
    LDA_(1, 0); LDB_(1, 0);
    if (cond) { STG_A(0, kt2, 2); STG_A(0, kt2, 3); }
    BARRIER(); PHTAIL(); MM_(0, 0); PHEND();
    LDB_(1, 1);
    if (cond) { STG_B(0, kt2, 0); STG_B(0, kt2, 1); }
    BARRIER(); PHTAIL(); MM_(0, 1); PHEND();
    LDA_(1, 1);
    if (cond) { STG_B(0, kt2, 2); STG_B(0, kt2, 3); }
    BARRIER(); PHTAIL(); MM_(1, 0); PHEND();
    if (cond) {
      STG_A(1, kt3, 0); STG_A(1, kt3, 1);
      VMC(2);
    }
    BARRIER(); PHTAIL(); MM_(1, 1); PHEND();
  }

  unsigned short* st = (unsigned short*)lds;
  __syncthreads();
#pragma unroll
  for (int pass = 0; pass < 2; ++pass) {
    if (wm == pass) {
#pragma unroll
      for (int n = 0; n < 4; ++n) {
        int col = wn * 64 + n * 16 + ar;
        float bv = bias[e * biasStride + n0 + col];
#pragma unroll
        for (int m = 0; m < 8; ++m) {
#pragma unroll
          for (int rr = 0; rr < 4; ++rr) {
            int row = m * 16 + kg * 4 + rr;
            float v = fast_gelu(acc[m][n][rr] + bv);
            st[row * 264 + col] = f2bf(v);
          }
        }
      }
    }
    __syncthreads();
    int row = tid >> 2, qq = tid & 3;
    unsigned short* drow =
        Hout + (long)(byl * 256 + pass * 128 + row) * ldh + n0 + qq * 64;
    const unsigned short* srow2 = st + row * 264 + qq * 64;
#pragma unroll
    for (int i = 0; i < 8; ++i)
      *(u16x8*)(drow + i * 8) = *(const u16x8*)(srow2 + i * 8);
    __syncthreads();
  }
#undef LDA_
#undef LDB_
#undef MM_
#undef PHTAIL
#undef PHEND
}

// ============ GEMM2 (8-phase): 256x256, BK=64, KI=24, 512 threads ===========
__global__ __launch_bounds__(512, 2)
void k_gemm2_8ph(const unsigned short* __restrict__ A, int lda,
                 const unsigned short* __restrict__ B, int ldb, long sB,
                 const int* __restrict__ counts,
                 const int* __restrict__ offsets, const int* __restrict__ tp,
                 int t0, const float* __restrict__ bias, int biasStride,
                 unsigned short* __restrict__ Yout,
                 const float* __restrict__ slot_w, int gx, int nwg)
{
  constexpr int KI = FDIM / 128;   // 24
  __shared__ __align__(16) char lds[131072];

  int orig = blockIdx.y * gx + blockIdx.x;
  int q = nwg >> 3, r = nwg & 7;
  int xcd = orig & 7, jj = orig >> 3;
  int wgid = (xcd < r ? xcd * (q + 1) : r * (q + 1) + (xcd - r) * q) + jj;
  const int RG = 16;
  int yT = nwg / gx;
  int gsize = gx * RG;
  int rg = wgid / gsize;
  int rem = wgid - rg * gsize;
  int rgs = yT - rg * RG; if (rgs > RG) rgs = RG;
  int bx = rem / rgs;
  int byl = rg * RG + (rem - bx * rgs);
  int by = t0 + byl;

  if (by >= tp[NEXP]) return;
  int e = 0;
  while (by >= tp[e + 1]) ++e;
  int cnt = counts[e];
  int rowbase = offsets[e];
  int m0 = (by - tp[e]) * 256;
  int n0 = bx * 256;

  const unsigned short* Bexp = B + (long)e * sB + (long)n0 * ldb;
  const unsigned short* Aexp = A + (long)(byl * 256) * lda;   // chunk-local H

  int tid = threadIdx.x;
  int lane = tid & 63, wid = tid >> 6;
  int wm = wid >> 2, wn = wid & 3;
  int ar = lane & 15, kg = lane >> 4;
  int arl = ar & 7;

  const char* pA[2][2];
  const char* pB[2][2];
#pragma unroll
  for (int d = 0; d < 2; ++d)
#pragma unroll
    for (int s = 0; s < 2; ++s) {
      int sw = (((s * 4 + kg) ^ arl) << 4);
      pA[d][s] = lds + d * 65536 + (wm * 128 + ar) * 128 + sw;
      pB[d][s] = lds + d * 65536 + 32768 + (wn * 64 + ar) * 128 + sw;
    }

  int srow = tid >> 3, schunk = tid & 7;
  int sswz = ((schunk ^ (srow & 7)) << 3);
  const unsigned short* srcA = Aexp + (long)srow * lda + sswz;
  const unsigned short* srcB = Bexp + (long)srow * ldb + sswz;

  auto STG_A = [&](int d, int kt, int g) {
    async16(srcA + (long)g * 64 * lda + kt * 64,
            lds + d * 65536 + g * 8192 + wid * 1024);
  };
  auto STG_B = [&](int d, int kt, int g) {
    async16(srcB + (long)g * 64 * ldb + kt * 64,
            lds + d * 65536 + 32768 + g * 8192 + wid * 1024);
  };

  f32x4 acc[8][4] = {};
  bf16x8 a[2][4], b[2][4];

#define LDA_(d, h)                                                   \
  _Pragma("unroll") for (int s = 0; s < 2; ++s)                      \
  _Pragma("unroll") for (int m = 0; m < 4; ++m)                      \
    a[s][m] = *(const bf16x8*)(pA[d][s] + (h) * 8192 + m * 2048);
#define LDB_(d, np)                                                  \
  _Pragma("unroll") for (int s = 0; s < 2; ++s)                      \
  _Pragma("unroll") for (int j = 0; j < 2; ++j)                      \
    b[s][(np) * 2 + j] = *(const bf16x8*)(pB[d][s] + ((np) * 2 + j) * 2048);
#define MM_(h, np)                                                   \
  _Pragma("unroll") for (int m = 0; m < 4; ++m)                      \
  _Pragma("unroll") for (int j = 0; j < 2; ++j) {                    \
    acc[(h)*4+m][(np)*2+j] = __builtin_amdgcn_mfma_f32_16x16x32_bf16(\
        a[0][m], b[0][(np)*2+j], acc[(h)*4+m][(np)*2+j], 0, 0, 0);   \
    acc[(h)*4+m][(np)*2+j] = __builtin_amdgcn_mfma_f32_16x16x32_bf16(\
        a[1][m], b[1][(np)*2+j], acc[(h)*4+m][(np)*2+j], 0, 0, 0); }
#define PHTAIL()  __builtin_amdgcn_s_setprio(1)
#define PHEND()   __builtin_amdgcn_s_setprio(0); BARRIER()

  STG_A(0, 0, 0); STG_A(0, 0, 1); STG_A(0, 0, 2); STG_A(0, 0, 3);
  STG_B(0, 0, 0); STG_B(0, 0, 1); STG_B(0, 0, 2); STG_B(0, 0, 3);
  STG_A(1, 1, 0); STG_A(1, 1, 1);
  VMC(2);
  BARRIER();

#pragma unroll 1
  for (int i = 0; i < KI; ++i) {
    const int kt1 = 2 * i + 1, kt2 = 2 * i + 2, kt3 = 2 * i + 3;
    const bool cond = (i + 1 < KI);
    LDA_(0, 0); LDB_(0, 0);
    STG_A(1, kt1, 2); STG_A(1, kt1, 3);
    BARRIER(); PHTAIL(); MM_(0, 0); PHEND();
    LDB_(0, 1);
    STG_B(1, kt1, 0); STG_B(1, kt1, 1);
    BARRIER(); PHTAIL(); MM_(0, 1); PHEND();
    LDA_(0, 1);
    STG_B(1, kt1, 2); STG_B(1, kt1, 3);
    BARRIER(); PHTAIL(); MM_(1, 0); PHEND();
    if (cond) {
      STG_A(0, kt2, 0); STG_A(0, kt2, 1);
      VMC(2);
    } else {
      VMC(0);
    }
    BARRIER(); PHTAIL(); MM_(1, 1); PHEND();
    LDA_(1, 0); LDB_(1, 0);
    if (cond) { STG_A(0, kt2, 2); STG_A(0, kt2, 3); }
    BARRIER(); PHTAIL(); MM_(0, 0); PHEND();
    LDB_(1, 1);
    if (cond) { STG_B(0, kt2, 0); STG_B(0, kt2, 1); }
    BARRIER(); PHTAIL(); MM_(0, 1); PHEND();
    LDA_(1, 1);
    if (cond) { STG_B(0, kt2, 2); STG_B(0, kt2, 3); }
    BARRIER(); PHTAIL(); MM_(1, 0); PHEND();
    if (cond) {
      STG_A(1, kt3, 0); STG_A(1, kt3, 1);
      VMC(2);
    }
    BARRIER(); PHTAIL(); MM_(1, 1); PHEND();
  }

  unsigned short* st = (unsigned short*)lds;
  __syncthreads();
#pragma unroll
  for (int pass = 0; pass < 2; ++pass) {
    if (wm == pass) {
#pragma unroll
      for (int m = 0; m < 8; ++m) {
#pragma unroll
        for (int rr = 0; rr < 4; ++rr) {
          int row = m * 16 + kg * 4 + rr;
          int grow = m0 + pass * 128 + row;
          float wt = (grow < cnt) ? slot_w[rowbase + grow] : 0.f;
#pragma unroll
          for (int n = 0; n < 4; ++n) {
            int col = wn * 64 + n * 16 + ar;
            float v = (acc[m][n][rr] + bias[e * biasStride + n0 + col]) * wt;
            st[row * 264 + col] = f2bf(v);
          }
        }
      }
    }
    __syncthreads();
    int row = tid >> 2, qq = tid & 3;
    int grow = m0 + pass * 128 + row;
    if (grow < cnt) {
      unsigned short* drow =
          Yout + (long)(rowbase + grow) * CDIM + n0 + qq * 64;
      const unsigned short* srow2 = st + row * 264 + qq * 64;
#pragma unroll
      for (int i = 0; i < 8; ++i)
        *(u16x8*)(drow + i * 8) = *(const u16x8*)(srow2 + i * 8);
    }
    __syncthreads();
  }
#undef LDA_
#undef LDB_
#undef MM_
#undef PHTAIL
#undef PHEND
}

// ============ GEMM2 (2-phase fallback): 128x128, 256 threads ================
__global__ __launch_bounds__(256, 3)
void k_gemm2(const unsigned short* __restrict__ A, int lda,
             const unsigned short* __restrict__ B, int ldb, long sB,
             int Ksteps, const int* __restrict__ counts,
             const int* __restrict__ offsets, const int* __restrict__ tp,
             int t0, const float* __restrict__ bias, int biasStride,
             unsigned short* __restrict__ Yout, const float* __restrict__ slot_w,
             int gx, int nwg)
{
  __shared__ __align__(16) char lds[3 * 16384];

  int orig = blockIdx.y * gx + blockIdx.x;
  int q = nwg >> 3, r = nwg & 7;
  int xcd = orig & 7, jj = orig >> 3;
  int wgid = (xcd < r ? xcd * (q + 1) : r * (q + 1) + (xcd - r) * q) + jj;
  const int RG = 16;
  int yT = nwg / gx;
  int gsize = gx * RG;
  int rg = wgid / gsize;
  int rem = wgid - rg * gsize;
  int rgs = yT - rg * RG; if (rgs > RG) rgs = RG;
  int bx = rem / rgs;
  int byl = rg * RG + (rem - bx * rgs);

  int t256l = byl >> 1, half = byl & 1;
  int by = t0 + t256l;
  if (by >= tp[NEXP]) return;
  int e = 0;
  while (by >= tp[e + 1]) ++e;
  int cnt = counts[e];
  int rowbase = offsets[e];
  int m0 = (by - tp[e]) * 256 + half * 128;
  if (m0 >= cnt) return;
  int n0 = bx * 128;

  const unsigned short* Bexp = B + (long)e * sB + (long)n0 * ldb;
  const unsigned short* Aexp = A + (long)(t256l * 256 + half * 128) * lda;

  int tid = threadIdx.x;
  int lane = tid & 63, wid = tid >> 6;
  int wm = wid >> 1, wn = wid & 1;
  int ar = lane & 15, kg = lane >> 4;
  int kgs = (kg ^ ((ar >> 1) & 3)) << 4;

  int rA0 = tid >> 2;
  int cA0 = tid & 3;
  int ksw = (cA0 ^ ((rA0 >> 1) & 3)) << 3;
  const unsigned short* As0 = Aexp + (long)rA0 * lda + ksw;
  const unsigned short* As1 = Aexp + (long)(rA0 + 64) * lda + ksw;
  const unsigned short* Bs0 = Bexp + (long)rA0 * ldb + ksw;
  const unsigned short* Bs1 = Bexp + (long)(rA0 + 64) * ldb + ksw;

  f32x4 acc[4][4] = {};

  auto STAGE = [&](int buf, int t) {
    char* bb = lds + buf * 16384;
    int ko = t * 32;
    async16(As0 + ko, bb + wid * 1024);
    async16(As1 + ko, bb + 4096 + wid * 1024);
    async16(Bs0 + ko, bb + 8192 + wid * 1024);
    async16(Bs1 + ko, bb + 12288 + wid * 1024);
  };

  STAGE(0, 0); STAGE(1, 1);
  int cur = 0, nxt2 = 2;

  for (int ks = 0; ks < Ksteps; ++ks) {
    if (ks + 1 < Ksteps) {
      asm volatile("s_waitcnt vmcnt(4)" ::: "memory");
    } else {
      asm volatile("s_waitcnt vmcnt(0)" ::: "memory");
    }
    __builtin_amdgcn_s_barrier();
    asm volatile("" ::: "memory");

    const char* bb = lds + cur * 16384;
    const char* bA = bb + (wm * 64 + ar) * 64 + kgs;
    const char* bB = bb + 8192 + (wn * 64 + ar) * 64 + kgs;
    bf16x8 af[4], bfr[4];
#pragma unroll
    for (int i = 0; i < 4; ++i) af[i] = *(const bf16x8*)(bA + i * 1024);
#pragma unroll
    for (int i = 0; i < 4; ++i) bfr[i] = *(const bf16x8*)(bB + i * 1024);

    if (ks + 2 < Ksteps) STAGE(nxt2, ks + 2);

#pragma unroll
    for (int mi = 0; mi < 4; ++mi)
#pragma unroll
      for (int ni = 0; ni < 4; ++ni)
        acc[mi][ni] = __builtin_amdgcn_mfma_f32_16x16x32_bf16(af[mi], bfr[ni],
                                                              acc[mi][ni], 0, 0, 0);
    cur = (cur == 2) ? 0 : cur + 1;
    nxt2 = (nxt2 == 2) ? 0 : nxt2 + 1;
  }

  unsigned short* st = (unsigned short*)lds;
  __syncthreads();

#pragma unroll
  for (int mi = 0; mi < 4; ++mi) {
#pragma unroll
    for (int rr = 0; rr < 4; ++rr) {
      int rowl = wm * 64 + mi * 16 + kg * 4 + rr;
      float wt = (m0 + rowl < cnt) ? slot_w[rowbase + m0 + rowl] : 0.f;
#pragma unroll
      for (int ni = 0; ni < 4; ++ni) {
        int col = wn * 64 + ni * 16 + ar;
        float v = (acc[mi][ni][rr] + bias[e * biasStride + n0 + col]) * wt;
        st[rowl * 136 + col] = f2bf(v);
      }
    }
  }
  __syncthreads();
  int row = tid >> 1, hh = tid & 1;
  if (m0 + row < cnt) {
    unsigned short* drow = Yout + (long)(rowbase + m0 + row) * CDIM + n0 + hh * 64;
    const unsigned short* srow = st + row * 136 + hh * 64;
#pragma unroll
    for (int i = 0; i < 8; ++i)
      *(u16x8*)(drow + i * 8) = *(const u16x8*)(srow + i * 8);
  }
}

// ---------------- final combine: out[t] = Y[slot0] + Y[slot1] ----------------
__global__ __launch_bounds__(256)
void k_combine(const unsigned short* __restrict__ Y,
               const int* __restrict__ tok2slot, float* __restrict__ out)
{
  int t = blockIdx.x * 4 + (threadIdx.x >> 6);
  int lane = threadIdx.x & 63;
  int s0 = tok2slot[2 * t], s1 = tok2slot[2 * t + 1];
  const ushort4* y0 = (const ushort4*)(Y + (size_t)s0 * CDIM);
  const ushort4* y1 = (const ushort4*)(Y + (size_t)s1 * CDIM);
  float4* o = (float4*)(out + (size_t)t * CDIM);
#pragma unroll
  for (int i = 0; i < 3; ++i) {
    ushort4 aa = y0[i * 64 + lane];
    ushort4 bb = y1[i * 64 + lane];
    float4 rr;
    rr.x = bf2f(aa.x) + bf2f(bb.x);
    rr.y = bf2f(aa.y) + bf2f(bb.y);
    rr.z = bf2f(aa.z) + bf2f(bb.z);
    rr.w = bf2f(aa.w) + bf2f(bb.w);
    o[i * 64 + lane] = rr;
  }
}

extern "C" void kernel_launch(void* const* d_in, const int* in_sizes, int n_in,
                              void* d_out, int out_size, void* d_ws, size_t ws_size,
                              hipStream_t stream) {
  const float* x        = (const float*)d_in[0];
  const float* router_w = (const float*)d_in[1];
  const float* w1       = (const float*)d_in[2];
  const float* b1       = (const float*)d_in[3];
  const float* w2       = (const float*)d_in[4];
  const float* b2       = (const float*)d_in[5];
  float* out = (float*)d_out;

  char* ws = (char*)d_ws;
  size_t off = 0;
  auto alloc = [&](size_t bytes) -> void* {
    void* p = ws + off;
    off = (off + bytes + 255) & ~(size_t)255;
    return p;
  };
  int*   counts     = (int*)alloc(NEXP * 4);
  int*   offsets    = (int*)alloc((NEXP + 1) * 4);
  int*   tp         = (int*)alloc((NEXP + 1) * 4);
  int*   tk_e       = (int*)alloc((size_t)NSLOT * 4);
  float* tk_w       = (float*)alloc((size_t)NSLOT * 4);
  int*   blockhist  = (int*)alloc((size_t)HBLK * NEXP * 4);
  int*   blockbase  = (int*)alloc((size_t)HBLK * NEXP * 4);
  int*   tok2slot   = (int*)alloc((size_t)NSLOT * 4);
  float* slot_w     = (float*)alloc((size_t)NSLOT * 4);
  int*   slot_pick  = (int*)alloc((size_t)NSLOT * 4);
  unsigned short* Yslot = (unsigned short*)alloc((size_t)NSLOT * CDIM * 2);
  unsigned short* w1t = (unsigned short*)alloc((size_t)NEXP * FDIM * CDIM * 2);
  unsigned short* w2t = (unsigned short*)alloc((size_t)NEXP * CDIM * FDIM * 2);
  unsigned short* Xbf = (unsigned short*)alloc((size_t)NTOK * CDIM * 2);
  // M-chunking ladder: 135 (single chunk) -> 68 -> 42 -> 21, ws-gated
  int TPC = MAXT256;
  if (off + (size_t)TPC * 256 * FDIM * 2 > ws_size) TPC = 68;
  if (off + (size_t)TPC * 256 * FDIM * 2 > ws_size) TPC = 42;
  if (off + (size_t)TPC * 256 * FDIM * 2 > ws_size) TPC = 21;
  bool big = (TPC >= 68);
  unsigned short* H = (unsigned short*)alloc((size_t)TPC * 256 * FDIM * 2);

  k_transpose<<<dim3(FDIM / 32, CDIM / 32, NEXP), 256, 0, stream>>>(w1, w1t, CDIM, FDIM);
  k_transpose<<<dim3(CDIM / 32, FDIM / 32, NEXP), 256, 0, stream>>>(w2, w2t, FDIM, CDIM);
  k_router<<<NTOK / 4, 256, 0, stream>>>(x, router_w, tk_e, tk_w);
  k_hist<<<HBLK, 256, 0, stream>>>(tk_e, blockhist);
  k_scan2<<<1, 512, 0, stream>>>(blockhist, counts, offsets, tp, blockbase);
  k_assign<<<HBLK, 256, 0, stream>>>(tk_e, tk_w, blockbase,
                                     tok2slot, slot_w, slot_pick);
  k_xbf16<<<NTOK * CDIM / 8 / 256, 256, 0, stream>>>(x, Xbf);

  for (int t0 = 0; t0 < MAXT256; t0 += TPC) {
    int yT = (MAXT256 - t0 < TPC) ? (MAXT256 - t0) : TPC;
    int gx1 = FDIM / 256;   // 12
    k_gemm1<<<dim3(gx1, yT), 512, 0, stream>>>(
        Xbf, slot_pick, w1t, CDIM, (long)FDIM * CDIM,
        counts, offsets, tp, t0, b1, FDIM, H, FDIM, gx1, gx1 * yT);
    if (big) {
      int gx2 = CDIM / 256;  // 3
      k_gemm2_8ph<<<dim3(gx2, yT), 512, 0, stream>>>(
          H, FDIM, w2t, FDIM, (long)CDIM * FDIM,
          counts, offsets, tp, t0, b2, CDIM, Yslot, slot_w, gx2, gx2 * yT);
    } else {
      int gx2 = CDIM / 128;  // 6
      k_gemm2<<<dim3(gx2, 2 * yT), 256, 0, stream>>>(
          H, FDIM, w2t, FDIM, (long)CDIM * FDIM, FDIM / 32,
          counts, offsets, tp, t0, b2, CDIM, Yslot, slot_w, gx2, gx2 * 2 * yT);
    }
  }
  k_combine<<<NTOK / 4, 256, 0, stream>>>(Yslot, tok2slot, out);
}

// Round 18
// 611.143 us; speedup vs baseline: 1.1479x; 1.0142x over previous
//
#include <hip/hip_runtime.h>
#include <hip/hip_bf16.h>

#define NTOK 16384
#define CDIM 768
#define FDIM 3072
#define NEXP 8
#define NSLOT 32768   // NTOK * TOPK
#define HBLK 128      // histogram blocks (NSLOT / 256)
#define MAXT256 135   // NSLOT/256 + NEXP - 1

typedef __attribute__((ext_vector_type(8))) short bf16x8;
typedef __attribute__((ext_vector_type(4))) float f32x4;
typedef __attribute__((ext_vector_type(8))) unsigned short u16x8;

__device__ __forceinline__ unsigned short f2bf(float f) {
  unsigned int u = __float_as_uint(f);
  u += 0x7FFFu + ((u >> 16) & 1u);   // RNE
  return (unsigned short)(u >> 16);
}
__device__ __forceinline__ float bf2f(unsigned short h) {
  return __uint_as_float((unsigned int)h << 16);
}

// GELU via Page-1977 logistic approx of Phi; |err| <= ~3e-4 << bf16 ulp of H
__device__ __forceinline__ float fast_gelu(float x) {
  float x2 = x * x;
  float z = x * __builtin_fmaf(0.070565402f, x2, 1.5975981f);
  float s = __builtin_amdgcn_rcpf(1.0f + __expf(-z));
  return x * s;
}

__device__ __forceinline__ void async16(const void* g, void* l) {
  __builtin_amdgcn_global_load_lds(
      (const __attribute__((address_space(1))) unsigned int*)g,
      (__attribute__((address_space(3))) unsigned int*)l, 16, 0, 0);
}

#define BARRIER() asm volatile("s_barrier" ::: "memory")
#define VMC(n)    asm volatile("s_waitcnt vmcnt(" #n ")" ::: "memory")

// ---------------- transpose + fp32->bf16 convert ----------------
__global__ __launch_bounds__(256)
void k_transpose(const float* __restrict__ src, unsigned short* __restrict__ dst,
                 int R, int Cc)
{
  __shared__ float tle[32][33];
  int e = blockIdx.z;
  int c0 = blockIdx.x * 32, r0 = blockIdx.y * 32;
  int tx = threadIdx.x & 31, ty = threadIdx.x >> 5;
  const float* s = src + (size_t)e * R * Cc;
  unsigned short* d = dst + (size_t)e * R * Cc;
#pragma unroll
  for (int i = 0; i < 4; ++i)
    tle[ty + i * 8][tx] = s[(size_t)(r0 + ty + i * 8) * Cc + c0 + tx];
  __syncthreads();
#pragma unroll
  for (int i = 0; i < 4; ++i)
    d[(size_t)(c0 + ty + i * 8) * R + r0 + tx] = f2bf(tle[tx][ty + i * 8]);
}

// ---------------- dense x -> bf16 copy ----------------
__global__ __launch_bounds__(256)
void k_xbf16(const float* __restrict__ x, unsigned short* __restrict__ Xbf)
{
  size_t i = (size_t)blockIdx.x * 256 + threadIdx.x;
  const float4* s = (const float4*)x;
  float4 v0 = s[2 * i], v1 = s[2 * i + 1];
  u16x8 h;
  h[0] = f2bf(v0.x); h[1] = f2bf(v0.y); h[2] = f2bf(v0.z); h[3] = f2bf(v0.w);
  h[4] = f2bf(v1.x); h[5] = f2bf(v1.y); h[6] = f2bf(v1.z); h[7] = f2bf(v1.w);
  ((u16x8*)Xbf)[i] = h;
}

// ---------------- router ----------------
__global__ __launch_bounds__(256)
void k_router(const float* __restrict__ x, const float* __restrict__ rw,
              int* __restrict__ tk_e, float* __restrict__ tk_w)
{
  __shared__ float srw[NEXP * CDIM];
  int tid = threadIdx.x;
#pragma unroll
  for (int i = 0; i < (NEXP * CDIM / 4) / 256; ++i)
    ((float4*)srw)[tid + i * 256] = ((const float4*)rw)[tid + i * 256];
  __syncthreads();
  int lane = tid & 63, wid = tid >> 6;
  int t = blockIdx.x * 4 + wid;
  float a[NEXP];
#pragma unroll
  for (int e = 0; e < NEXP; ++e) a[e] = 0.f;
  const float* xr = x + (size_t)t * CDIM;
#pragma unroll
  for (int c = 0; c < CDIM / 64; ++c) {
    float xv = xr[c * 64 + lane];
#pragma unroll
    for (int e = 0; e < NEXP; ++e) a[e] += xv * srw[e * CDIM + c * 64 + lane];
  }
#pragma unroll
  for (int e = 0; e < NEXP; ++e) {
#pragma unroll
    for (int off = 32; off; off >>= 1) a[e] += __shfl_xor(a[e], off);
  }
  if (lane == 0) {
    int i0 = 0; float l0 = a[0];
#pragma unroll
    for (int e = 1; e < NEXP; ++e) if (a[e] > l0) { l0 = a[e]; i0 = e; }
    int i1 = -1; float l1 = -1e30f;
#pragma unroll
    for (int e = 0; e < NEXP; ++e) if (e != i0 && a[e] > l1) { l1 = a[e]; i1 = e; }
    float w0 = 1.f / (1.f + expf(l1 - l0));
    tk_e[2 * t] = i0;     tk_e[2 * t + 1] = i1;
    tk_w[2 * t] = w0;     tk_w[2 * t + 1] = 1.f - w0;
  }
}

// ---------------- per-block expert histogram ----------------
__global__ __launch_bounds__(256)
void k_hist(const int* __restrict__ tk_e, int* __restrict__ blockhist)
{
  __shared__ int h[NEXP];
  int tid = threadIdx.x;
  if (tid < NEXP) h[tid] = 0;
  __syncthreads();
  int e = tk_e[blockIdx.x * 256 + tid];
  atomicAdd(&h[e], 1);
  __syncthreads();
  if (tid < NEXP) blockhist[blockIdx.x * NEXP + tid] = h[tid];
}

// ---------------- scan (tp in 256-row tiles) ----------------
__global__ __launch_bounds__(512)
void k_scan2(const int* __restrict__ blockhist, int* __restrict__ counts,
             int* __restrict__ offsets, int* __restrict__ tp,
             int* __restrict__ blockbase)
{
  __shared__ int ltot[NEXP];
  __shared__ int loff[NEXP + 1];
  int tid = threadIdx.x;
  int lane = tid & 63, e = tid >> 6;
  int o0 = blockhist[lane * NEXP + e];
  int o1 = blockhist[(64 + lane) * NEXP + e];
  int h0 = o0, h1 = o1;
#pragma unroll
  for (int d = 1; d < 64; d <<= 1) { int v = __shfl_up(h0, d); if (lane >= d) h0 += v; }
  int s0 = __shfl(h0, 63);
#pragma unroll
  for (int d = 1; d < 64; d <<= 1) { int v = __shfl_up(h1, d); if (lane >= d) h1 += v; }
  h1 += s0;
  if (lane == 63) ltot[e] = h1;
  __syncthreads();
  if (tid == 0) {
    loff[0] = 0;
    int tpv = 0; tp[0] = 0;
    for (int k = 0; k < NEXP; ++k) {
      loff[k + 1] = loff[k] + ltot[k];
      counts[k] = ltot[k];
      offsets[k] = loff[k];
      tpv += (ltot[k] + 255) / 256;
      tp[k + 1] = tpv;
    }
    offsets[NEXP] = loff[NEXP];
  }
  __syncthreads();
  int base = loff[e];
  blockbase[lane * NEXP + e]        = base + h0 - o0;
  blockbase[(64 + lane) * NEXP + e] = base + h1 - o1;
}

// ---------------- stable slot assign ----------------
__global__ __launch_bounds__(256)
void k_assign(const int* __restrict__ tk_e, const float* __restrict__ tk_w,
              const int* __restrict__ blockbase,
              int* __restrict__ tok2slot, float* __restrict__ slot_w,
              int* __restrict__ slot_pick)
{
  __shared__ int eh[256];
  int b = blockIdx.x, tid = threadIdx.x;
  int pick = b * 256 + tid;
  int e = tk_e[pick];
  eh[tid] = e;
  __syncthreads();
  int rank = 0;
  for (int j = 0; j < tid; ++j) rank += (eh[j] == e);
  int slot = blockbase[b * NEXP + e] + rank;
  tok2slot[pick] = slot;          // pick = 2*token + kk
  slot_w[slot] = tk_w[pick];
  slot_pick[slot] = pick;
}

// ============ GEMM1: 256x256 tile, BK=64, 8-phase, 512 thr, 2 M-tiles/block =
// Each block runs the full K-loop+epilogue for TWO consecutive M-tiles with
// the same bx: B-panel stages for tile 2 are L2-hot; prologue/tail amortized.
__global__ __launch_bounds__(512, 2)
void k_gemm1(const unsigned short* __restrict__ Xbf,
             const int* __restrict__ slot_pick,
             const unsigned short* __restrict__ B, int ldb, long sB,
             const int* __restrict__ counts,
             const int* __restrict__ offsets, const int* __restrict__ tp,
             int t0, const float* __restrict__ bias, int biasStride,
             unsigned short* __restrict__ Hout, int ldh, int gx, int nwg)
{
  constexpr int KI = CDIM / 128;   // 6 — compile-time
  __shared__ __align__(16) char lds[131072];

  // XCD-aware bijective swizzle (m204) + row-group decode over tile-PAIRS
  int orig = blockIdx.y * gx + blockIdx.x;
  int q = nwg >> 3, r = nwg & 7;
  int xcd = orig & 7, jj = orig >> 3;
  int wgid = (xcd < r ? xcd * (q + 1) : r * (q + 1) + (xcd - r) * q) + jj;
  const int RG = 16;
  int yTp = nwg / gx;                  // pair count
  int gsize = gx * RG;
  int rg = wgid / gsize;
  int rem = wgid - rg * gsize;
  int rgs = yTp - rg * RG; if (rgs > RG) rgs = RG;
  int bx = rem / rgs;
  int bylp = rg * RG + (rem - bx * rgs);
  int n0 = bx * 256;

  int tid = threadIdx.x;
  int lane = tid & 63, wid = tid >> 6;
  int wm = wid >> 2, wn = wid & 3;              // 2M x 4N waves
  int ar = lane & 15, kg = lane >> 4;
  int arl = ar & 7;

  const char* pA[2][2];
  const char* pB[2][2];
#pragma unroll
  for (int d = 0; d < 2; ++d)
#pragma unroll
    for (int s = 0; s < 2; ++s) {
      int sw = (((s * 4 + kg) ^ arl) << 4);
      pA[d][s] = lds + d * 65536 + (wm * 128 + ar) * 128 + sw;
      pB[d][s] = lds + d * 65536 + 32768 + (wn * 64 + ar) * 128 + sw;
    }

  int srow = tid >> 3, schunk = tid & 7;
  int sswz = ((schunk ^ (srow & 7)) << 3);
  const unsigned short* srcB =
      B + (long)n0 * ldb + (long)srow * ldb + sswz;   // + e*sB per tile

#define LDA_(d, h)                                                   \
  _Pragma("unroll") for (int s = 0; s < 2; ++s)                      \
  _Pragma("unroll") for (int m = 0; m < 4; ++m)                      \
    a[s][m] = *(const bf16x8*)(pA[d][s] + (h) * 8192 + m * 2048);
#define LDB_(d, np)                                                  \
  _Pragma("unroll") for (int s = 0; s < 2; ++s)                      \
  _Pragma("unroll") for (int j = 0; j < 2; ++j)                      \
    b[s][(np) * 2 + j] = *(const bf16x8*)(pB[d][s] + ((np) * 2 + j) * 2048);
#define MM_(h, np)                                                   \
  _Pragma("unroll") for (int m = 0; m < 4; ++m)                      \
  _Pragma("unroll") for (int j = 0; j < 2; ++j) {                    \
    acc[(h)*4+m][(np)*2+j] = __builtin_amdgcn_mfma_f32_16x16x32_bf16(\
        a[0][m], b[0][(np)*2+j], acc[(h)*4+m][(np)*2+j], 0, 0, 0);   \
    acc[(h)*4+m][(np)*2+j] = __builtin_amdgcn_mfma_f32_16x16x32_bf16(\
        a[1][m], b[1][(np)*2+j], acc[(h)*4+m][(np)*2+j], 0, 0, 0); }
#define PHTAIL()  __builtin_amdgcn_s_setprio(1)
#define PHEND()   __builtin_amdgcn_s_setprio(0); BARRIER()

#pragma unroll 1
  for (int mt = 0; mt < 2; ++mt) {
    int byl = bylp * 2 + mt;
    int by = t0 + byl;
    if (by >= tp[NEXP]) break;
    int e = 0;
    while (by >= tp[e + 1]) ++e;
    int rowbase = offsets[e];
    int m0 = (by - tp[e]) * 256;

    const unsigned short* srcBe = srcB + (long)e * sB;
    const unsigned short* srcAg[4];
#pragma unroll
    for (int g = 0; g < 4; ++g) {
      int sidx = rowbase + m0 + srow + g * 64;
      if (sidx > NSLOT - 1) sidx = NSLOT - 1;
      int tok = slot_pick[sidx] >> 1;
      srcAg[g] = Xbf + (long)tok * CDIM + sswz;
    }

    auto STG_A = [&](int d, int kt, int g) {
      async16(srcAg[g] + kt * 64,
              lds + d * 65536 + g * 8192 + wid * 1024);
    };
    auto STG_B = [&](int d, int kt, int g) {
      async16(srcBe + (long)g * 64 * ldb + kt * 64,
              lds + d * 65536 + 32768 + g * 8192 + wid * 1024);
    };

    f32x4 acc[8][4] = {};
    bf16x8 a[2][4], b[2][4];

    STG_A(0, 0, 0); STG_A(0, 0, 1); STG_A(0, 0, 2); STG_A(0, 0, 3);
    STG_B(0, 0, 0); STG_B(0, 0, 1); STG_B(0, 0, 2); STG_B(0, 0, 3);
    STG_A(1, 1, 0); STG_A(1, 1, 1);
    VMC(2);
    BARRIER();

#pragma unroll
    for (int i = 0; i < KI; ++i) {
      const int kt1 = 2 * i + 1, kt2 = 2 * i + 2, kt3 = 2 * i + 3;
      const bool cond = (i + 1 < KI);
      LDA_(0, 0); LDB_(0, 0);
      STG_A(1, kt1, 2); STG_A(1, kt1, 3);
      BARRIER(); PHTAIL(); MM_(0, 0); PHEND();
      LDB_(0, 1);
      STG_B(1, kt1, 0); STG_B(1, kt1, 1);
      BARRIER(); PHTAIL(); MM_(0, 1); PHEND();
      LDA_(0, 1);
      STG_B(1, kt1, 2); STG_B(1, kt1, 3);
      BARRIER(); PHTAIL(); MM_(1, 0); PHEND();
      if (cond) {
        STG_A(0, kt2, 0); STG_A(0, kt2, 1);
        VMC(2);
      } else {
        VMC(0);
      }
      BARRIER(); PHTAIL(); MM_(1, 1); PHEND();
      LDA_(1, 0); LDB_(1, 0);
      if (cond) { STG_A(0, kt2, 2); STG_A(0, kt2, 3); }
      BARRIER(); PHTAIL(); MM_(0, 0); PHEND();
      LDB_(1, 1);
      if (cond) { STG_B(0, kt2, 0); STG_B(0, kt2, 1); }
      BARRIER(); PHTAIL(); MM_(0, 1); PHEND();
      LDA_(1, 1);
      if (cond) { STG_B(0, kt2, 2); STG_B(0, kt2, 3); }
      BARRIER(); PHTAIL(); MM_(1, 0); PHEND();
      if (cond) {
        STG_A(1, kt3, 0); STG_A(1, kt3, 1);
        VMC(2);
      }
      BARRIER(); PHTAIL(); MM_(1, 1); PHEND();
    }

    unsigned short* st = (unsigned short*)lds;
    __syncthreads();
#pragma unroll
    for (int pass = 0; pass < 2; ++pass) {
      if (wm == pass) {
#pragma unroll
        for (int n = 0; n < 4; ++n) {
          int col = wn * 64 + n * 16 + ar;
          float bv = bias[e * biasStride + n0 + col];
#pragma unroll
          for (int m = 0; m < 8; ++m) {
#pragma unroll
            for (int rr = 0; rr < 4; ++rr) {
              int row = m * 16 + kg * 4 + rr;
              float v = fast_gelu(acc[m][n][rr] + bv);
              st[row * 264 + col] = f2bf(v);
            }
          }
        }
      }
      __syncthreads();
      int row = tid >> 2, qq = tid & 3;
      unsigned short* drow =
          Hout + (long)(byl * 256 + pass * 128 + row) * ldh + n0 + qq * 64;
      const unsigned short* srow2 = st + row * 264 + qq * 64;
#pragma unroll
      for (int i = 0; i < 8; ++i)
        *(u16x8*)(drow + i * 8) = *(const u16x8*)(srow2 + i * 8);
      __syncthreads();
    }
  }
#undef LDA_
#undef LDB_
#undef MM_
#undef PHTAIL
#undef PHEND
}

// ============ GEMM2 (8-phase): 256x256, BK=64, KI=24, 512 threads ===========
__global__ __launch_bounds__(512, 2)
void k_gemm2_8ph(const unsigned short* __restrict__ A, int lda,
                 const unsigned short* __restrict__ B, int ldb, long sB,
                 const int* __restrict__ counts,
                 const int* __restrict__ offsets, const int* __restrict__ tp,
                 int t0, const float* __restrict__ bias, int biasStride,
                 unsigned short* __restrict__ Yout,
                 const float* __restrict__ slot_w, int gx, int nwg)
{
  constexpr int KI = FDIM / 128;   // 24
  __shared__ __align__(16) char lds[131072];

  int orig = blockIdx.y * gx + blockIdx.x;
  int q = nwg >> 3, r = nwg & 7;
  int xcd = orig & 7, jj = orig >> 3;
  int wgid = (xcd < r ? xcd * (q + 1) : r * (q + 1) + (xcd - r) * q) + jj;
  const int RG = 16;
  int yT = nwg / gx;
  int gsize = gx * RG;
  int rg = wgid / gsize;
  int rem = wgid - rg * gsize;
  int rgs = yT - rg * RG; if (rgs > RG) rgs = RG;
  int bx = rem / rgs;
  int byl = rg * RG + (rem - bx * rgs);
  int by = t0 + byl;

  if (by >= tp[NEXP]) return;
  int e = 0;
  while (by >= tp[e + 1]) ++e;
  int cnt = counts[e];
  int rowbase = offsets[e];
  int m0 = (by - tp[e]) * 256;
  int n0 = bx * 256;

  const unsigned short* Bexp = B + (long)e * sB + (long)n0 * ldb;
  const unsigned short* Aexp = A + (long)(byl * 256) * lda;   // chunk-local H

  int tid = threadIdx.x;
  int lane = tid & 63, wid = tid >> 6;
  int wm = wid >> 2, wn = wid & 3;
  int ar = lane & 15, kg = lane >> 4;
  int arl = ar & 7;

  const char* pA[2][2];
  const char* pB[2][2];
#pragma unroll
  for (int d = 0; d < 2; ++d)
#pragma unroll
    for (int s = 0; s < 2; ++s) {
      int sw = (((s * 4 + kg) ^ arl) << 4);
      pA[d][s] = lds + d * 65536 + (wm * 128 + ar) * 128 + sw;
      pB[d][s] = lds + d * 65536 + 32768 + (wn * 64 + ar) * 128 + sw;
    }

  int srow = tid >> 3, schunk = tid & 7;
  int sswz = ((schunk ^ (srow & 7)) << 3);
  const unsigned short* srcA = Aexp + (long)srow * lda + sswz;
  const unsigned short* srcB = Bexp + (long)srow * ldb + sswz;

  auto STG_A = [&](int d, int kt, int g) {
    async16(srcA + (long)g * 64 * lda + kt * 64,
            lds + d * 65536 + g * 8192 + wid * 1024);
  };
  auto STG_B = [&](int d, int kt, int g) {
    async16(srcB + (long)g * 64 * ldb + kt * 64,
            lds + d * 65536 + 32768 + g * 8192 + wid * 1024);
  };

  f32x4 acc[8][4] = {};
  bf16x8 a[2][4], b[2][4];

#define LDA_(d, h)                                                   \
  _Pragma("unroll") for (int s = 0; s < 2; ++s)                      \
  _Pragma("unroll") for (int m = 0; m < 4; ++m)                      \
    a[s][m] = *(const bf16x8*)(pA[d][s] + (h) * 8192 + m * 2048);
#define LDB_(d, np)                                                  \
  _Pragma("unroll") for (int s = 0; s < 2; ++s)                      \
  _Pragma("unroll") for (int j = 0; j < 2; ++j)                      \
    b[s][(np) * 2 + j] = *(const bf16x8*)(pB[d][s] + ((np) * 2 + j) * 2048);
#define MM_(h, np)                                                   \
  _Pragma("unroll") for (int m = 0; m < 4; ++m)                      \
  _Pragma("unroll") for (int j = 0; j < 2; ++j) {                    \
    acc[(h)*4+m][(np)*2+j] = __builtin_amdgcn_mfma_f32_16x16x32_bf16(\
        a[0][m], b[0][(np)*2+j], acc[(h)*4+m][(np)*2+j], 0, 0, 0);   \
    acc[(h)*4+m][(np)*2+j] = __builtin_amdgcn_mfma_f32_16x16x32_bf16(\
        a[1][m], b[1][(np)*2+j], acc[(h)*4+m][(np)*2+j], 0, 0, 0); }
#define PHTAIL()  __builtin_amdgcn_s_setprio(1)
#define PHEND()   __builtin_amdgcn_s_setprio(0); BARRIER()

  STG_A(0, 0, 0); STG_A(0, 0, 1); STG_A(0, 0, 2); STG_A(0, 0, 3);
  STG_B(0, 0, 0); STG_B(0, 0, 1); STG_B(0, 0, 2); STG_B(0, 0, 3);
  STG_A(1, 1, 0); STG_A(1, 1, 1);
  VMC(2);
  BARRIER();

#pragma unroll 1
  for (int i = 0; i < KI; ++i) {
    const int kt1 = 2 * i + 1, kt2 = 2 * i + 2, kt3 = 2 * i + 3;
    const bool cond = (i + 1 < KI);
    LDA_(0, 0); LDB_(0, 0);
    STG_A(1, kt1, 2); STG_A(1, kt1, 3);
    BARRIER(); PHTAIL(); MM_(0, 0); PHEND();
    LDB_(0, 1);
    STG_B(1, kt1, 0); STG_B(1, kt1, 1);
    BARRIER(); PHTAIL(); MM_(0, 1); PHEND();
    LDA_(0, 1);
    STG_B(1, kt1, 2); STG_B(1, kt1, 3);
    BARRIER(); PHTAIL(); MM_(1, 0); PHEND();
    if (cond) {
      STG_A(0, kt2, 0); STG_A(0, kt2, 1);
      VMC(2);
    } else {
      VMC(0);
    }
    BARRIER(); PHTAIL(); MM_(1, 1); PHEND();
    LDA_(1, 0); LDB_(1, 0);
    if (cond) { STG_A(0, kt2, 2); STG_A(0, kt2, 3); }
    BARRIER(); PHTAIL(); MM_(0, 0); PHEND();
    LDB_(1, 1);
    if (cond) { STG_B(0, kt2, 0); STG_B(0, kt2, 1); }
    BARRIER(); PHTAIL(); MM_(0, 1); PHEND();
    LDA_(1, 1);
    if (cond) { STG_B(0, kt2, 2); STG_B(0, kt2, 3); }
    BARRIER(); PHTAIL(); MM_(1, 0); PHEND();
    if (cond) {
      STG_A(1, kt3, 0); STG_A(1, kt3, 1);
      VMC(2);
    }
    BARRIER(); PHTAIL(); MM_(1, 1); PHEND();
  }

  unsigned short* st = (unsigned short*)lds;
  __syncthreads();
#pragma unroll
  for (int pass = 0; pass < 2; ++pass) {
    if (wm == pass) {
#pragma unroll
      for (int m = 0; m < 8; ++m) {
#pragma unroll
        for (int rr = 0; rr < 4; ++rr) {
          int row = m * 16 + kg * 4 + rr;
          int grow = m0 + pass * 128 + row;
          float wt = (grow < cnt) ? slot_w[rowbase + grow] : 0.f;
#pragma unroll
          for (int n = 0; n < 4; ++n) {
            int col = wn * 64 + n * 16 + ar;
            float v = (acc[m][n][rr] + bias[e * biasStride + n0 + col]) * wt;
            st[row * 264 + col] = f2bf(v);
          }
        }
      }
    }
    __syncthreads();
    int row = tid >> 2, qq = tid & 3;
    int grow = m0 + pass * 128 + row;
    if (grow < cnt) {
      unsigned short* drow =
          Yout + (long)(rowbase + grow) * CDIM + n0 + qq * 64;
      const unsigned short* srow2 = st + row * 264 + qq * 64;
#pragma unroll
      for (int i = 0; i < 8; ++i)
        *(u16x8*)(drow + i * 8) = *(const u16x8*)(srow2 + i * 8);
    }
    __syncthreads();
  }
#undef LDA_
#undef LDB_
#undef MM_
#undef PHTAIL
#undef PHEND
}

// ============ GEMM2 (2-phase fallback): 128x128, 256 threads ================
__global__ __launch_bounds__(256, 3)
void k_gemm2(const unsigned short* __restrict__ A, int lda,
             const unsigned short* __restrict__ B, int ldb, long sB,
             int Ksteps, const int* __restrict__ counts,
             const int* __restrict__ offsets, const int* __restrict__ tp,
             int t0, const float* __restrict__ bias, int biasStride,
             unsigned short* __restrict__ Yout, const float* __restrict__ slot_w,
             int gx, int nwg)
{
  __shared__ __align__(16) char lds[3 * 16384];

  int orig = blockIdx.y * gx + blockIdx.x;
  int q = nwg >> 3, r = nwg & 7;
  int xcd = orig & 7, jj = orig >> 3;
  int wgid = (xcd < r ? xcd * (q + 1) : r * (q + 1) + (xcd - r) * q) + jj;
  const int RG = 16;
  int yT = nwg / gx;
  int gsize = gx * RG;
  int rg = wgid / gsize;
  int rem = wgid - rg * gsize;
  int rgs = yT - rg * RG; if (rgs > RG) rgs = RG;
  int bx = rem / rgs;
  int byl = rg * RG + (rem - bx * rgs);

  int t256l = byl >> 1, half = byl & 1;
  int by = t0 + t256l;
  if (by >= tp[NEXP]) return;
  int e = 0;
  while (by >= tp[e + 1]) ++e;
  int cnt = counts[e];
  int rowbase = offsets[e];
  int m0 = (by - tp[e]) * 256 + half * 128;
  if (m0 >= cnt) return;
  int n0 = bx * 128;

  const unsigned short* Bexp = B + (long)e * sB + (long)n0 * ldb;
  const unsigned short* Aexp = A + (long)(t256l * 256 + half * 128) * lda;

  int tid = threadIdx.x;
  int lane = tid & 63, wid = tid >> 6;
  int wm = wid >> 1, wn = wid & 1;
  int ar = lane & 15, kg = lane >> 4;
  int kgs = (kg ^ ((ar >> 1) & 3)) << 4;

  int rA0 = tid >> 2;
  int cA0 = tid & 3;
  int ksw = (cA0 ^ ((rA0 >> 1) & 3)) << 3;
  const unsigned short* As0 = Aexp + (long)rA0 * lda + ksw;
  const unsigned short* As1 = Aexp + (long)(rA0 + 64) * lda + ksw;
  const unsigned short* Bs0 = Bexp + (long)rA0 * ldb + ksw;
  const unsigned short* Bs1 = Bexp + (long)(rA0 + 64) * ldb + ksw;

  f32x4 acc[4][4] = {};

  auto STAGE = [&](int buf, int t) {
    char* bb = lds + buf * 16384;
    int ko = t * 32;
    async16(As0 + ko, bb + wid * 1024);
    async16(As1 + ko, bb + 4096 + wid * 1024);
    async16(Bs0 + ko, bb + 8192 + wid * 1024);
    async16(Bs1 + ko, bb + 12288 + wid * 1024);
  };

  STAGE(0, 0); STAGE(1, 1);
  int cur = 0, nxt2 = 2;

  for (int ks = 0; ks < Ksteps; ++ks) {
    if (ks + 1 < Ksteps) {
      asm volatile("s_waitcnt vmcnt(4)" ::: "memory");
    } else {
      asm volatile("s_waitcnt vmcnt(0)" ::: "memory");
    }
    __builtin_amdgcn_s_barrier();
    asm volatile("" ::: "memory");

    const char* bb = lds + cur * 16384;
    const char* bA = bb + (wm * 64 + ar) * 64 + kgs;
    const char* bB = bb + 8192 + (wn * 64 + ar) * 64 + kgs;
    bf16x8 af[4], bfr[4];
#pragma unroll
    for (int i = 0; i < 4; ++i) af[i] = *(const bf16x8*)(bA + i * 1024);
#pragma unroll
    for (int i = 0; i < 4; ++i) bfr[i] = *(const bf16x8*)(bB + i * 1024);

    if (ks + 2 < Ksteps) STAGE(nxt2, ks + 2);

#pragma unroll
    for (int mi = 0; mi < 4; ++mi)
#pragma unroll
      for (int ni = 0; ni < 4; ++ni)
        acc[mi][ni] = __builtin_amdgcn_mfma_f32_16x16x32_bf16(af[mi], bfr[ni],
                                                              acc[mi][ni], 0, 0, 0);
    cur = (cur == 2) ? 0 : cur + 1;
    nxt2 = (nxt2 == 2) ? 0 : nxt2 + 1;
  }

  unsigned short* st = (unsigned short*)lds;
  __syncthreads();

#pragma unroll
  for (int mi = 0; mi < 4; ++mi) {
#pragma unroll
    for (int rr = 0; rr < 4; ++rr) {
      int rowl = wm * 64 + mi * 16 + kg * 4 + rr;
      float wt = (m0 + rowl < cnt) ? slot_w[rowbase + m0 + rowl] : 0.f;
#pragma unroll
      for (int ni = 0; ni < 4; ++ni) {
        int col = wn * 64 + ni * 16 + ar;
        float v = (acc[mi][ni][rr] + bias[e * biasStride + n0 + col]) * wt;
        st[rowl * 136 + col] = f2bf(v);
      }
    }
  }
  __syncthreads();
  int row = tid >> 1, hh = tid & 1;
  if (m0 + row < cnt) {
    unsigned short* drow = Yout + (long)(rowbase + m0 + row) * CDIM + n0 + hh * 64;
    const unsigned short* srow = st + row * 136 + hh * 64;
#pragma unroll
    for (int i = 0; i < 8; ++i)
      *(u16x8*)(drow + i * 8) = *(const u16x8*)(srow + i * 8);
  }
}

// ---------------- final combine: out[t] = Y[slot0] + Y[slot1] ----------------
__global__ __launch_bounds__(256)
void k_combine(const unsigned short* __restrict__ Y,
               const int* __restrict__ tok2slot, float* __restrict__ out)
{
  int t = blockIdx.x * 4 + (threadIdx.x >> 6);
  int lane = threadIdx.x & 63;
  int s0 = tok2slot[2 * t], s1 = tok2slot[2 * t + 1];
  const ushort4* y0 = (const ushort4*)(Y + (size_t)s0 * CDIM);
  const ushort4* y1 = (const ushort4*)(Y + (size_t)s1 * CDIM);
  float4* o = (float4*)(out + (size_t)t * CDIM);
#pragma unroll
  for (int i = 0; i < 3; ++i) {
    ushort4 aa = y0[i * 64 + lane];
    ushort4 bb = y1[i * 64 + lane];
    float4 rr;
    rr.x = bf2f(aa.x) + bf2f(bb.x);
    rr.y = bf2f(aa.y) + bf2f(bb.y);
    rr.z = bf2f(aa.z) + bf2f(bb.z);
    rr.w = bf2f(aa.w) + bf2f(bb.w);
    o[i * 64 + lane] = rr;
  }
}

extern "C" void kernel_launch(void* const* d_in, const int* in_sizes, int n_in,
                              void* d_out, int out_size, void* d_ws, size_t ws_size,
                              hipStream_t stream) {
  const float* x        = (const float*)d_in[0];
  const float* router_w = (const float*)d_in[1];
  const float* w1       = (const float*)d_in[2];
  const float* b1       = (const float*)d_in[3];
  const float* w2       = (const float*)d_in[4];
  const float* b2       = (const float*)d_in[5];
  float* out = (float*)d_out;

  char* ws = (char*)d_ws;
  size_t off = 0;
  auto alloc = [&](size_t bytes) -> void* {
    void* p = ws + off;
    off = (off + bytes + 255) & ~(size_t)255;
    return p;
  };
  int*   counts     = (int*)alloc(NEXP * 4);
  int*   offsets    = (int*)alloc((NEXP + 1) * 4);
  int*   tp         = (int*)alloc((NEXP + 1) * 4);
  int*   tk_e       = (int*)alloc((size_t)NSLOT * 4);
  float* tk_w       = (float*)alloc((size_t)NSLOT * 4);
  int*   blockhist  = (int*)alloc((size_t)HBLK * NEXP * 4);
  int*   blockbase  = (int*)alloc((size_t)HBLK * NEXP * 4);
  int*   tok2slot   = (int*)alloc((size_t)NSLOT * 4);
  float* slot_w     = (float*)alloc((size_t)NSLOT * 4);
  int*   slot_pick  = (int*)alloc((size_t)NSLOT * 4);
  unsigned short* Yslot = (unsigned short*)alloc((size_t)NSLOT * CDIM * 2);
  unsigned short* w1t = (unsigned short*)alloc((size_t)NEXP * FDIM * CDIM * 2);
  unsigned short* w2t = (unsigned short*)alloc((size_t)NEXP * CDIM * FDIM * 2);
  unsigned short* Xbf = (unsigned short*)alloc((size_t)NTOK * CDIM * 2);
  // M-chunking ladder: 68 -> 42 -> 21, ws-gated
  int TPC = 68;
  if (off + (size_t)TPC * 256 * FDIM * 2 > ws_size) TPC = 42;
  if (off + (size_t)TPC * 256 * FDIM * 2 > ws_size) TPC = 21;
  bool big = (TPC >= 68);
  unsigned short* H = (unsigned short*)alloc((size_t)TPC * 256 * FDIM * 2);

  k_transpose<<<dim3(FDIM / 32, CDIM / 32, NEXP), 256, 0, stream>>>(w1, w1t, CDIM, FDIM);
  k_transpose<<<dim3(CDIM / 32, FDIM / 32, NEXP), 256, 0, stream>>>(w2, w2t, FDIM, CDIM);
  k_router<<<NTOK / 4, 256, 0, stream>>>(x, router_w, tk_e, tk_w);
  k_hist<<<HBLK, 256, 0, stream>>>(tk_e, blockhist);
  k_scan2<<<1, 512, 0, stream>>>(blockhist, counts, offsets, tp, blockbase);
  k_assign<<<HBLK, 256, 0, stream>>>(tk_e, tk_w, blockbase,
                                     tok2slot, slot_w, slot_pick);
  k_xbf16<<<NTOK * CDIM / 8 / 256, 256, 0, stream>>>(x, Xbf);

  for (int t0 = 0; t0 < MAXT256; t0 += TPC) {
    int yT = (MAXT256 - t0 < TPC) ? (MAXT256 - t0) : TPC;
    int gx1 = FDIM / 256;   // 12
    int yTp = (yT + 1) / 2; // tile pairs
    k_gemm1<<<dim3(gx1, yTp), 512, 0, stream>>>(
        Xbf, slot_pick, w1t, CDIM, (long)FDIM * CDIM,
        counts, offsets, tp, t0, b1, FDIM, H, FDIM, gx1, gx1 * yTp);
    if (big) {
      int gx2 = CDIM / 256;  // 3
      k_gemm2_8ph<<<dim3(gx2, yT), 512, 0, stream>>>(
          H, FDIM, w2t, FDIM, (long)CDIM * FDIM,
          counts, offsets, tp, t0, b2, CDIM, Yslot, slot_w, gx2, gx2 * yT);
    } else {
      int gx2 = CDIM / 128;  // 6
      k_gemm2<<<dim3(gx2, 2 * yT), 256, 0, stream>>>(
          H, FDIM, w2t, FDIM, (long)CDIM * FDIM, FDIM / 32,
          counts, offsets, tp, t0, b2, CDIM, Yslot, slot_w, gx2, gx2 * 2 * yT);
    }
  }
  k_combine<<<NTOK / 4, 256, 0, stream>>>(Yslot, tok2slot, out);
}